// Round 2
// baseline (521.770 us; speedup 1.0000x reference)
//
#include <hip/hip_runtime.h>

#define TPB 256

__device__ __forceinline__ float bf2f(unsigned short u) {
    unsigned int x = ((unsigned int)u) << 16;
    return __builtin_bit_cast(float, x);
}
__device__ __forceinline__ unsigned short f2bf(float f) {
    unsigned int u = __builtin_bit_cast(unsigned int, f);
    unsigned int r = u + 0x7FFFu + ((u >> 16) & 1u);   // round-to-nearest-even
    return (unsigned short)(r >> 16);
}

// Build combined weight matrix Wc[64][cols]: cols = K*64 (spline kernels) + 64 (root lw).
__global__ void build_wc_kernel(const float* __restrict__ W, const float* __restrict__ lw,
                                float* __restrict__ Wc, int K, int cols) {
    int t = blockIdx.x * TPB + threadIdx.x;
    int total = 64 * cols;
    if (t >= total) return;
    int i = t / cols;
    int o = t - i * cols;
    int ko = K * 64;
    float v;
    if (o < ko) v = W[(o >> 6) * 4096 + i * 64 + (o & 63)];   // W[k][i][o64]
    else        v = lw[i * 64 + (o - ko)];
    Wc[t] = v;
}

__global__ void count_kernel(const int* __restrict__ dst, int* __restrict__ counts, int E) {
    int e = blockIdx.x * TPB + threadIdx.x;
    if (e < E) atomicAdd(&counts[dst[e]], 1);
}

// Block-level exclusive scan, 1024 elements per block (4 per thread).
__global__ void scan1_kernel(const int* __restrict__ counts, int* __restrict__ offsets,
                             int* __restrict__ bsum, int n) {
    __shared__ int s[TPB];
    int t = threadIdx.x;
    int base = blockIdx.x * 1024 + t * 4;
    int v[4];
#pragma unroll
    for (int q = 0; q < 4; ++q) v[q] = (base + q < n) ? counts[base + q] : 0;
    int tsum = v[0] + v[1] + v[2] + v[3];
    s[t] = tsum;
    __syncthreads();
    for (int off = 1; off < TPB; off <<= 1) {
        int x = (t >= off) ? s[t - off] : 0;
        __syncthreads();
        s[t] += x;
        __syncthreads();
    }
    int acc = s[t] - tsum;  // exclusive prefix within block
#pragma unroll
    for (int q = 0; q < 4; ++q) {
        if (base + q < n) offsets[base + q] = acc;
        acc += v[q];
    }
    if (t == TPB - 1) bsum[blockIdx.x] = s[TPB - 1];
}

// Scan block sums (nblk <= 256), in place, exclusive.
__global__ void scan2_kernel(int* __restrict__ bsum, int nblk) {
    __shared__ int s[TPB];
    int t = threadIdx.x;
    int v = (t < nblk) ? bsum[t] : 0;
    s[t] = v;
    __syncthreads();
    for (int off = 1; off < TPB; off <<= 1) {
        int x = (t >= off) ? s[t - off] : 0;
        __syncthreads();
        s[t] += x;
        __syncthreads();
    }
    if (t < nblk) bsum[t] = s[t] - v;
}

__global__ void scan3_kernel(int* __restrict__ offsets, int* __restrict__ fillp,
                             const int* __restrict__ bsum, int n, int E) {
    int base = blockIdx.x * 1024 + threadIdx.x * 4;
    int add = bsum[blockIdx.x];
#pragma unroll
    for (int q = 0; q < 4; ++q) {
        int idx = base + q;
        if (idx < n) {
            int o = offsets[idx] + add;
            offsets[idx] = o;
            fillp[idx] = o;
        }
    }
    if (blockIdx.x == 0 && threadIdx.x == 0) offsets[n] = E;
}

__global__ void fill_kernel(const int* __restrict__ src, const int* __restrict__ dst,
                            const float* __restrict__ u, int* __restrict__ fillp,
                            int* __restrict__ csr_src, float* __restrict__ csr_u, int E) {
    int e = blockIdx.x * TPB + threadIdx.x;
    if (e >= E) return;
    int d = dst[e];
    int pos = atomicAdd(&fillp[d], 1);
    csr_src[pos] = src[e];
    csr_u[pos] = u[e];
}

// Z[n][c..c+15] = sum_i X[n][i] * Wc[i][c..c+15], stored bf16.
// One thread per (node, 16-col chunk). W addresses are block-uniform -> s_load;
// inner loop is pure v_fmac_f32 with SGPR operands.
__global__ void gemm_kernel(const float* __restrict__ X, const float* __restrict__ Wc,
                            unsigned short* __restrict__ Z, int N, int cols) {
    int n = blockIdx.x * TPB + threadIdx.x;
    if (n >= N) return;
    int c = blockIdx.y * 16;
    float acc[16];
#pragma unroll
    for (int j = 0; j < 16; ++j) acc[j] = 0.f;
    const float* xrow = X + (size_t)n * 64;
#pragma unroll
    for (int i4 = 0; i4 < 64; i4 += 4) {
        float4 xq = *reinterpret_cast<const float4*>(xrow + i4);
        const float* wr = Wc + (size_t)i4 * cols + c;
        float xs[4] = {xq.x, xq.y, xq.z, xq.w};
#pragma unroll
        for (int ii = 0; ii < 4; ++ii) {
#pragma unroll
            for (int j = 0; j < 16; ++j)
                acc[j] = fmaf(xs[ii], wr[ii * cols + j], acc[j]);
        }
    }
    unsigned short us[16];
#pragma unroll
    for (int j = 0; j < 16; ++j) us[j] = f2bf(acc[j]);
    uint4* zp = reinterpret_cast<uint4*>(Z + (size_t)n * cols + c);
    zp[0] = reinterpret_cast<const uint4*>(us)[0];
    zp[1] = reinterpret_cast<const uint4*>(us)[1];
}

// One wave per dst node; lane = channel. Gather bf16 Z rows of CSR sources,
// linear B-spline interpolation (fp32 accum), mean, + root + bias, relu.
__global__ void agg_kernel(const unsigned short* __restrict__ Z, const int* __restrict__ offsets,
                           const int* __restrict__ csr_src, const float* __restrict__ csr_u,
                           const float* __restrict__ bias, float* __restrict__ out,
                           int N, int K, int cols) {
    int gw = (blockIdx.x * TPB + threadIdx.x) >> 6;
    int lane = threadIdx.x & 63;
    if (gw >= N) return;
    int beg = offsets[gw];
    int end = offsets[gw + 1];
    float km1 = (float)(K - 1);
    int km1i = K - 1;
    float acc = 0.f;
    for (int j = beg; j < end; ++j) {
        int s = csr_src[j];
        float u = csr_u[j];
        float v = u * km1;
        float f = floorf(v);
        f = fminf(fmaxf(f, 0.f), km1);
        int i0 = (int)f;
        int i1 = min(i0 + 1, km1i);
        float frac = v - f;
        const unsigned short* zr = Z + (size_t)s * cols;
        float z0 = bf2f(zr[i0 * 64 + lane]);
        float z1 = bf2f(zr[i1 * 64 + lane]);
        acc = fmaf(1.f - frac, z0, acc);
        acc = fmaf(frac, z1, acc);
    }
    int cnt = end - beg;
    float inv = 1.f / (float)(cnt > 0 ? cnt : 1);
    float root = bf2f(Z[(size_t)gw * cols + (size_t)(K * 64) + lane]);
    float r = fmaf(acc, inv, root + bias[lane]);
    out[(size_t)gw * 64 + lane] = fmaxf(r, 0.f);
}

extern "C" void kernel_launch(void* const* d_in, const int* in_sizes, int n_in,
                              void* d_out, int out_size, void* d_ws, size_t ws_size,
                              hipStream_t stream) {
    const float* x   = (const float*)d_in[0];
    const int*   ei  = (const int*)d_in[1];      // int64 in reference -> int32 from harness
    const float* ea  = (const float*)d_in[2];
    const float* W1  = (const float*)d_in[3];
    const float* lw1 = (const float*)d_in[4];
    const float* b1  = (const float*)d_in[5];
    const float* W2  = (const float*)d_in[6];
    const float* lw2 = (const float*)d_in[7];
    const float* b2  = (const float*)d_in[8];

    const int N = in_sizes[0] / 64;
    const int E = in_sizes[1] / 2;
    const int K = in_sizes[3] / 4096;      // K * 64 * 64
    const int cols = (K + 1) * 64;         // K spline blocks + root block

    char* p = (char*)d_ws;
    auto carve = [&](size_t bytes) -> void* {
        void* r = (void*)p;
        p += (bytes + 255) & ~(size_t)255;
        return r;
    };
    unsigned short* Z = (unsigned short*)carve((size_t)N * cols * sizeof(unsigned short));
    float* Wc1     = (float*)carve((size_t)64 * cols * sizeof(float));
    float* Wc2     = (float*)carve((size_t)64 * cols * sizeof(float));
    int*   counts  = (int*)carve((size_t)N * sizeof(int));
    int*   offsets = (int*)carve((size_t)(N + 1) * sizeof(int));
    int*   bsum    = (int*)carve(256 * sizeof(int));
    int*   fillp   = (int*)carve((size_t)N * sizeof(int));
    int*   csr_src = (int*)carve((size_t)E * sizeof(int));
    float* csr_u   = (float*)carve((size_t)E * sizeof(float));

    const int* src = ei;
    const int* dst = ei + E;

    hipMemsetAsync(counts, 0, (size_t)N * sizeof(int), stream);

    int wcTotal = 64 * cols;
    int wcBlocks = (wcTotal + TPB - 1) / TPB;
    build_wc_kernel<<<wcBlocks, TPB, 0, stream>>>(W1, lw1, Wc1, K, cols);
    build_wc_kernel<<<wcBlocks, TPB, 0, stream>>>(W2, lw2, Wc2, K, cols);

    int eBlocks = (E + TPB - 1) / TPB;
    count_kernel<<<eBlocks, TPB, 0, stream>>>(dst, counts, E);

    int nscan = (N + 1023) / 1024;
    scan1_kernel<<<nscan, TPB, 0, stream>>>(counts, offsets, bsum, N);
    scan2_kernel<<<1, TPB, 0, stream>>>(bsum, nscan);
    scan3_kernel<<<nscan, TPB, 0, stream>>>(offsets, fillp, bsum, N, E);

    fill_kernel<<<eBlocks, TPB, 0, stream>>>(src, dst, ea, fillp, csr_src, csr_u, E);

    dim3 ggrid((N + TPB - 1) / TPB, cols / 16);
    int aBlocks = (N + 3) / 4;

    // Layer 1
    gemm_kernel<<<ggrid, TPB, 0, stream>>>(x, Wc1, Z, N, cols);
    agg_kernel<<<aBlocks, TPB, 0, stream>>>(Z, offsets, csr_src, csr_u, b1, (float*)d_out, N, K, cols);
    // Layer 2 (input h lives in d_out; fully overwritten by the second agg)
    gemm_kernel<<<ggrid, TPB, 0, stream>>>((const float*)d_out, Wc2, Z, N, cols);
    agg_kernel<<<aBlocks, TPB, 0, stream>>>(Z, offsets, csr_src, csr_u, b2, (float*)d_out, N, K, cols);
}

// Round 3
// 353.007 us; speedup vs baseline: 1.4781x; 1.4781x over previous
//
#include <hip/hip_runtime.h>

#define TPB 256

__device__ __forceinline__ float bf2f(unsigned short u) {
    unsigned int x = ((unsigned int)u) << 16;
    return __builtin_bit_cast(float, x);
}
__device__ __forceinline__ unsigned short f2bf(float f) {
    unsigned int u = __builtin_bit_cast(unsigned int, f);
    unsigned int r = u + 0x7FFFu + ((u >> 16) & 1u);   // round-to-nearest-even
    return (unsigned short)(r >> 16);
}

// fp32 -> packed bf16 (4 floats / thread)
__global__ void cvt_bf16_kernel(const float* __restrict__ in, uint2* __restrict__ out, int n4) {
    int t = blockIdx.x * TPB + threadIdx.x;
    if (t >= n4) return;
    float4 v = reinterpret_cast<const float4*>(in)[t];
    uint2 r;
    r.x = (unsigned int)f2bf(v.x) | ((unsigned int)f2bf(v.y) << 16);
    r.y = (unsigned int)f2bf(v.z) | ((unsigned int)f2bf(v.w) << 16);
    out[t] = r;
}

// Wcat[192][64] fp32: rows 0..127 interleaved {W0 row c, W1 row c}, rows 128..191 = lw.
__global__ void build_wcat_kernel(const float* __restrict__ W, const float* __restrict__ lw,
                                  float* __restrict__ Wcat) {
    int t = blockIdx.x * TPB + threadIdx.x;
    if (t >= 192 * 64) return;
    int r = t >> 6;
    int o = t & 63;
    float v;
    if (r < 128) {
        int k = r & 1, ci = r >> 1;
        v = W[k * 4096 + ci * 64 + o];     // W[k][ci][o]
    } else {
        v = lw[(r - 128) * 64 + o];
    }
    Wcat[t] = v;
}

__global__ void count_kernel(const int* __restrict__ dst, int* __restrict__ counts, int E) {
    int e = blockIdx.x * TPB + threadIdx.x;
    if (e < E) atomicAdd(&counts[dst[e]], 1);
}

// Block-level exclusive scan, 1024 elements per block (4 per thread).
__global__ void scan1_kernel(const int* __restrict__ counts, int* __restrict__ offsets,
                             int* __restrict__ bsum, int n) {
    __shared__ int s[TPB];
    int t = threadIdx.x;
    int base = blockIdx.x * 1024 + t * 4;
    int v[4];
#pragma unroll
    for (int q = 0; q < 4; ++q) v[q] = (base + q < n) ? counts[base + q] : 0;
    int tsum = v[0] + v[1] + v[2] + v[3];
    s[t] = tsum;
    __syncthreads();
    for (int off = 1; off < TPB; off <<= 1) {
        int x = (t >= off) ? s[t - off] : 0;
        __syncthreads();
        s[t] += x;
        __syncthreads();
    }
    int acc = s[t] - tsum;
#pragma unroll
    for (int q = 0; q < 4; ++q) {
        if (base + q < n) offsets[base + q] = acc;
        acc += v[q];
    }
    if (t == TPB - 1) bsum[blockIdx.x] = s[TPB - 1];
}

__global__ void scan2_kernel(int* __restrict__ bsum, int nblk) {
    __shared__ int s[TPB];
    int t = threadIdx.x;
    int v = (t < nblk) ? bsum[t] : 0;
    s[t] = v;
    __syncthreads();
    for (int off = 1; off < TPB; off <<= 1) {
        int x = (t >= off) ? s[t - off] : 0;
        __syncthreads();
        s[t] += x;
        __syncthreads();
    }
    if (t < nblk) bsum[t] = s[t] - v;
}

__global__ void scan3_kernel(int* __restrict__ offsets, int* __restrict__ fillp,
                             const int* __restrict__ bsum, int n, int E) {
    int base = blockIdx.x * 1024 + threadIdx.x * 4;
    int add = bsum[blockIdx.x];
#pragma unroll
    for (int q = 0; q < 4; ++q) {
        int idx = base + q;
        if (idx < n) {
            int o = offsets[idx] + add;
            offsets[idx] = o;
            fillp[idx] = o;
        }
    }
    if (blockIdx.x == 0 && threadIdx.x == 0) offsets[n] = E;
}

__global__ void fill_kernel(const int* __restrict__ src, const int* __restrict__ dst,
                            const float* __restrict__ u, int* __restrict__ fillp,
                            int2* __restrict__ csr, int E) {
    int e = blockIdx.x * TPB + threadIdx.x;
    if (e >= E) return;
    int d = dst[e];
    int pos = atomicAdd(&fillp[d], 1);
    csr[pos] = make_int2(src[e], __float_as_int(u[e]));
}

// One wave per dst node; lane = channel. Gather bf16 feature rows; accumulate
// A0 = sum (1-u) feat[src], A1 = sum u feat[src] (exact for K=2); mean; store
// interleaved bf16 pairs (one uint per lane).
__global__ void agg_kernel(const unsigned short* __restrict__ feat,
                           const int* __restrict__ offsets,
                           const int2* __restrict__ csr,
                           unsigned int* __restrict__ A, int N) {
    int gw = (blockIdx.x * TPB + threadIdx.x) >> 6;
    int lane = threadIdx.x & 63;
    if (gw >= N) return;
    int beg = offsets[gw], end = offsets[gw + 1];
    float a0 = 0.f, a1 = 0.f;
    int j = beg;
    for (; j + 2 <= end; j += 2) {
        int2 e0 = csr[j];
        int2 e1 = csr[j + 1];
        float u0 = __int_as_float(e0.y);
        float u1 = __int_as_float(e1.y);
        float f0 = bf2f(feat[(size_t)e0.x * 64 + lane]);
        float f1 = bf2f(feat[(size_t)e1.x * 64 + lane]);
        a0 = fmaf(f0, 1.f - u0, a0);
        a1 = fmaf(f0, u0, a1);
        a0 = fmaf(f1, 1.f - u1, a0);
        a1 = fmaf(f1, u1, a1);
    }
    if (j < end) {
        int2 e0 = csr[j];
        float u0 = __int_as_float(e0.y);
        float f0 = bf2f(feat[(size_t)e0.x * 64 + lane]);
        a0 = fmaf(f0, 1.f - u0, a0);
        a1 = fmaf(f0, u0, a1);
    }
    int cnt = end - beg;
    float inv = 1.f / (float)(cnt > 0 ? cnt : 1);
    unsigned int packed = (unsigned int)f2bf(a0 * inv) | ((unsigned int)f2bf(a1 * inv) << 16);
    A[(size_t)gw * 64 + lane] = packed;
}

// out[n][c..c+15] = relu( sum_i q[i]*Wcat[i][c..c+15] + b ), q = [A pairs(128) | feat(64)] bf16.
// Thread per (node, 16-col chunk); weight addresses block-uniform -> s_load.
__global__ void gemm_kernel(const unsigned int* __restrict__ A,
                            const unsigned short* __restrict__ feat,
                            const float* __restrict__ Wcat, const float* __restrict__ bias,
                            unsigned short* __restrict__ out_bf, float* __restrict__ out_f,
                            int N, int write_f32) {
    int n = blockIdx.x * TPB + threadIdx.x;
    if (n >= N) return;
    int c = blockIdx.y * 16;
    float acc[16];
#pragma unroll
    for (int j = 0; j < 16; ++j) acc[j] = 0.f;

    const uint4* ap = reinterpret_cast<const uint4*>(A + (size_t)n * 64);
#pragma unroll 4
    for (int b8 = 0; b8 < 16; ++b8) {         // inputs 0..127 (interleaved A0/A1)
        uint4 q = ap[b8];
        unsigned int w[4] = {q.x, q.y, q.z, q.w};
        int ibase = b8 * 8;
#pragma unroll
        for (int h = 0; h < 4; ++h) {
            float flo = bf2f((unsigned short)(w[h] & 0xFFFF));
            float fhi = bf2f((unsigned short)(w[h] >> 16));
            const float* w0 = Wcat + (size_t)(ibase + 2 * h) * 64 + c;
            const float* w1 = w0 + 64;
#pragma unroll
            for (int j = 0; j < 16; ++j) acc[j] = fmaf(flo, w0[j], acc[j]);
#pragma unroll
            for (int j = 0; j < 16; ++j) acc[j] = fmaf(fhi, w1[j], acc[j]);
        }
    }
    const uint4* fp = reinterpret_cast<const uint4*>(feat + (size_t)n * 64);
#pragma unroll 4
    for (int b8 = 0; b8 < 8; ++b8) {          // inputs 128..191 (root features)
        uint4 q = fp[b8];
        unsigned int w[4] = {q.x, q.y, q.z, q.w};
        int ibase = 128 + b8 * 8;
#pragma unroll
        for (int h = 0; h < 4; ++h) {
            float flo = bf2f((unsigned short)(w[h] & 0xFFFF));
            float fhi = bf2f((unsigned short)(w[h] >> 16));
            const float* w0 = Wcat + (size_t)(ibase + 2 * h) * 64 + c;
            const float* w1 = w0 + 64;
#pragma unroll
            for (int j = 0; j < 16; ++j) acc[j] = fmaf(flo, w0[j], acc[j]);
#pragma unroll
            for (int j = 0; j < 16; ++j) acc[j] = fmaf(fhi, w1[j], acc[j]);
        }
    }
#pragma unroll
    for (int j = 0; j < 16; ++j) acc[j] = fmaxf(acc[j] + bias[c + j], 0.f);

    if (write_f32) {
        float* op = out_f + (size_t)n * 64 + c;
#pragma unroll
        for (int j4 = 0; j4 < 16; j4 += 4)
            *reinterpret_cast<float4*>(op + j4) =
                make_float4(acc[j4], acc[j4 + 1], acc[j4 + 2], acc[j4 + 3]);
    } else {
        unsigned short us[16];
#pragma unroll
        for (int j = 0; j < 16; ++j) us[j] = f2bf(acc[j]);
        uint4* op = reinterpret_cast<uint4*>(out_bf + (size_t)n * 64 + c);
        op[0] = reinterpret_cast<const uint4*>(us)[0];
        op[1] = reinterpret_cast<const uint4*>(us)[1];
    }
}

extern "C" void kernel_launch(void* const* d_in, const int* in_sizes, int n_in,
                              void* d_out, int out_size, void* d_ws, size_t ws_size,
                              hipStream_t stream) {
    const float* x   = (const float*)d_in[0];
    const int*   ei  = (const int*)d_in[1];      // int64 in reference -> int32 from harness
    const float* ea  = (const float*)d_in[2];
    const float* W1  = (const float*)d_in[3];
    const float* lw1 = (const float*)d_in[4];
    const float* b1  = (const float*)d_in[5];
    const float* W2  = (const float*)d_in[6];
    const float* lw2 = (const float*)d_in[7];
    const float* b2  = (const float*)d_in[8];

    const int N = in_sizes[0] / 64;
    const int E = in_sizes[1] / 2;

    char* p = (char*)d_ws;
    auto carve = [&](size_t bytes) -> void* {
        void* r = (void*)p;
        p += (bytes + 255) & ~(size_t)255;
        return r;
    };
    unsigned short* xb   = (unsigned short*)carve((size_t)N * 64 * 2);
    unsigned short* h    = (unsigned short*)carve((size_t)N * 64 * 2);
    unsigned int*   A    = (unsigned int*)carve((size_t)N * 64 * 4);
    float* Wcat1  = (float*)carve(192 * 64 * 4);
    float* Wcat2  = (float*)carve(192 * 64 * 4);
    int*   counts = (int*)carve((size_t)N * 4);
    int*   offsets= (int*)carve((size_t)(N + 1) * 4);
    int*   bsum   = (int*)carve(256 * 4);
    int*   fillp  = (int*)carve((size_t)N * 4);
    int2*  csr    = (int2*)carve((size_t)E * 8);

    const int* src = ei;
    const int* dst = ei + E;

    hipMemsetAsync(counts, 0, (size_t)N * 4, stream);

    int n4 = N * 64 / 4;
    cvt_bf16_kernel<<<(n4 + TPB - 1) / TPB, TPB, 0, stream>>>(x, (uint2*)xb, n4);

    build_wcat_kernel<<<(192 * 64 + TPB - 1) / TPB, TPB, 0, stream>>>(W1, lw1, Wcat1);
    build_wcat_kernel<<<(192 * 64 + TPB - 1) / TPB, TPB, 0, stream>>>(W2, lw2, Wcat2);

    int eBlocks = (E + TPB - 1) / TPB;
    count_kernel<<<eBlocks, TPB, 0, stream>>>(dst, counts, E);

    int nscan = (N + 1023) / 1024;
    scan1_kernel<<<nscan, TPB, 0, stream>>>(counts, offsets, bsum, N);
    scan2_kernel<<<1, TPB, 0, stream>>>(bsum, nscan);
    scan3_kernel<<<nscan, TPB, 0, stream>>>(offsets, fillp, bsum, N, E);

    fill_kernel<<<eBlocks, TPB, 0, stream>>>(src, dst, ea, fillp, csr, E);

    int aBlocks = (N + 3) / 4;          // 4 waves (nodes) per block
    dim3 ggrid((N + TPB - 1) / TPB, 4); // 4 out-col chunks of 16

    // Layer 1: agg on xb, then fused GEMM -> h (bf16)
    agg_kernel<<<aBlocks, TPB, 0, stream>>>(xb, offsets, csr, A, N);
    gemm_kernel<<<ggrid, TPB, 0, stream>>>(A, xb, Wcat1, b1, h, nullptr, N, 0);
    // Layer 2: agg on h, then fused GEMM -> d_out (fp32)
    agg_kernel<<<aBlocks, TPB, 0, stream>>>(h, offsets, csr, A, N);
    gemm_kernel<<<ggrid, TPB, 0, stream>>>(A, h, Wcat2, b2, nullptr, (float*)d_out, N, 1);
}

// Round 4
// 271.176 us; speedup vs baseline: 1.9241x; 1.3018x over previous
//
#include <hip/hip_runtime.h>

#define TPB 256
// NOTE: packing assumes N < 131072 (17-bit node ids) and u in [0,1]. Holds for
// this problem (N=100000, edge_attr ~ U[0,1)).

__device__ __forceinline__ float bf2f(unsigned short u) {
    unsigned int x = ((unsigned int)u) << 16;
    return __builtin_bit_cast(float, x);
}
__device__ __forceinline__ unsigned short f2bf(float f) {
    unsigned int u = __builtin_bit_cast(unsigned int, f);
    unsigned int r = u + 0x7FFFu + ((u >> 16) & 1u);   // round-to-nearest-even
    return (unsigned short)(r >> 16);
}

// fp32 -> packed bf16 (4 floats / thread); also zeroes counts[0..N).
__global__ void cvt_bf16_kernel(const float* __restrict__ in, uint2* __restrict__ out, int n4,
                                int* __restrict__ counts, int N) {
    int t = blockIdx.x * TPB + threadIdx.x;
    if (t < N) counts[t] = 0;
    if (t >= n4) return;
    float4 v = reinterpret_cast<const float4*>(in)[t];
    uint2 r;
    r.x = (unsigned int)f2bf(v.x) | ((unsigned int)f2bf(v.y) << 16);
    r.y = (unsigned int)f2bf(v.z) | ((unsigned int)f2bf(v.w) << 16);
    out[t] = r;
}

// Both layers' Wcat in one launch. Layout per layer: rows 0..127 interleaved
// {W0 row c, W1 row c}, rows 128..191 = lw. Wcat size 2*192*64 fp32.
__global__ void build_wcat2_kernel(const float* __restrict__ W1, const float* __restrict__ lw1,
                                   const float* __restrict__ W2, const float* __restrict__ lw2,
                                   float* __restrict__ Wcat) {
    int t = blockIdx.x * TPB + threadIdx.x;
    if (t >= 2 * 192 * 64) return;
    int which = t / (192 * 64);
    int r = (t >> 6) % 192;
    int o = t & 63;
    const float* W  = which ? W2  : W1;
    const float* lw = which ? lw2 : lw1;
    float v = (r < 128) ? W[(r & 1) * 4096 + (r >> 1) * 64 + o] : lw[(r - 128) * 64 + o];
    Wcat[t] = v;
}

// counts + per-edge rank + precomputed packed payload (src | u15<<17).
__global__ void count_kernel(const int* __restrict__ dst, const int* __restrict__ src,
                             const float* __restrict__ u, int* __restrict__ counts,
                             unsigned int* __restrict__ combined,
                             unsigned int* __restrict__ payload, int E) {
    int e = blockIdx.x * TPB + threadIdx.x;
    if (e >= E) return;
    int d = dst[e];
    int r = atomicAdd(&counts[d], 1);
    combined[e] = (unsigned int)d | ((unsigned int)r << 17);
    unsigned int uq = (unsigned int)__float2int_rn(u[e] * 32767.f);
    payload[e] = (unsigned int)src[e] | (uq << 17);
}

// Block-level exclusive scan, 1024 elements per block (4 per thread).
__global__ void scan1_kernel(const int* __restrict__ counts, int* __restrict__ offsets,
                             int* __restrict__ bsum, int n) {
    __shared__ int s[TPB];
    int t = threadIdx.x;
    int base = blockIdx.x * 1024 + t * 4;
    int v[4];
#pragma unroll
    for (int q = 0; q < 4; ++q) v[q] = (base + q < n) ? counts[base + q] : 0;
    int tsum = v[0] + v[1] + v[2] + v[3];
    s[t] = tsum;
    __syncthreads();
    for (int off = 1; off < TPB; off <<= 1) {
        int x = (t >= off) ? s[t - off] : 0;
        __syncthreads();
        s[t] += x;
        __syncthreads();
    }
    int acc = s[t] - tsum;
#pragma unroll
    for (int q = 0; q < 4; ++q) {
        if (base + q < n) offsets[base + q] = acc;
        acc += v[q];
    }
    if (t == TPB - 1) bsum[blockIdx.x] = s[TPB - 1];
}

__global__ void scan2_kernel(int* __restrict__ bsum, int nblk) {
    __shared__ int s[TPB];
    int t = threadIdx.x;
    int v = (t < nblk) ? bsum[t] : 0;
    s[t] = v;
    __syncthreads();
    for (int off = 1; off < TPB; off <<= 1) {
        int x = (t >= off) ? s[t - off] : 0;
        __syncthreads();
        s[t] += x;
        __syncthreads();
    }
    if (t < nblk) bsum[t] = s[t] - v;
}

__global__ void scan3_kernel(int* __restrict__ offsets, const int* __restrict__ bsum,
                             int n, int E) {
    int base = blockIdx.x * 1024 + threadIdx.x * 4;
    int add = bsum[blockIdx.x];
#pragma unroll
    for (int q = 0; q < 4; ++q) {
        int idx = base + q;
        if (idx < n) offsets[idx] += add;
    }
    if (blockIdx.x == 0 && threadIdx.x == 0) offsets[n] = E;
}

// Phase-partitioned scatter: phase p handles dst in [p*16384, (p+1)*16384) so the
// live csr write window (~650 KB) stays L2-resident -> write combining works.
// No atomics (rank precomputed in count_kernel).
__global__ void fill_kernel(const unsigned int* __restrict__ combined,
                            const unsigned int* __restrict__ payload,
                            const int* __restrict__ offsets,
                            unsigned int* __restrict__ csr, int E, int nphases) {
    int stride = gridDim.x * TPB;
    for (int p = 0; p < nphases; ++p) {
        for (int e = blockIdx.x * TPB + threadIdx.x; e < E; e += stride) {
            unsigned int c = combined[e];
            int d = c & 0x1FFFF;
            if ((d >> 14) == p) {
                int pos = offsets[d] + (int)(c >> 17);
                csr[pos] = payload[e];
            }
        }
    }
}

// One wave per dst node; lane = channel. Gather bf16 feature rows; accumulate
// A0 = sum (1-u) feat[src], A1 = sum u feat[src] (exact for K=2); mean; store
// interleaved bf16 pairs (one uint per lane).
__global__ void agg_kernel(const unsigned short* __restrict__ feat,
                           const int* __restrict__ offsets,
                           const unsigned int* __restrict__ csr,
                           unsigned int* __restrict__ A, int N) {
    int gw = (blockIdx.x * TPB + threadIdx.x) >> 6;
    int lane = threadIdx.x & 63;
    if (gw >= N) return;
    int beg = offsets[gw], end = offsets[gw + 1];
    const float us = 1.f / 32767.f;
    float a0 = 0.f, a1 = 0.f;
    int j = beg;
    for (; j + 4 <= end; j += 4) {
        unsigned int c0 = csr[j], c1 = csr[j + 1], c2 = csr[j + 2], c3 = csr[j + 3];
        float f0 = bf2f(feat[(size_t)(c0 & 0x1FFFF) * 64 + lane]);
        float f1 = bf2f(feat[(size_t)(c1 & 0x1FFFF) * 64 + lane]);
        float f2 = bf2f(feat[(size_t)(c2 & 0x1FFFF) * 64 + lane]);
        float f3 = bf2f(feat[(size_t)(c3 & 0x1FFFF) * 64 + lane]);
        float u0 = (float)(c0 >> 17) * us, u1 = (float)(c1 >> 17) * us;
        float u2 = (float)(c2 >> 17) * us, u3 = (float)(c3 >> 17) * us;
        a0 = fmaf(f0, 1.f - u0, a0); a1 = fmaf(f0, u0, a1);
        a0 = fmaf(f1, 1.f - u1, a0); a1 = fmaf(f1, u1, a1);
        a0 = fmaf(f2, 1.f - u2, a0); a1 = fmaf(f2, u2, a1);
        a0 = fmaf(f3, 1.f - u3, a0); a1 = fmaf(f3, u3, a1);
    }
    for (; j < end; ++j) {
        unsigned int c0 = csr[j];
        float u0 = (float)(c0 >> 17) * us;
        float f0 = bf2f(feat[(size_t)(c0 & 0x1FFFF) * 64 + lane]);
        a0 = fmaf(f0, 1.f - u0, a0); a1 = fmaf(f0, u0, a1);
    }
    int cnt = end - beg;
    float inv = 1.f / (float)(cnt > 0 ? cnt : 1);
    unsigned int packed = (unsigned int)f2bf(a0 * inv) | ((unsigned int)f2bf(a1 * inv) << 16);
    A[(size_t)gw * 64 + lane] = packed;
}

// out[n][c..c+15] = relu( sum_i q[i]*Wcat[i][c..c+15] + b ), q = [A pairs(128) | feat(64)] bf16.
__global__ void gemm_kernel(const unsigned int* __restrict__ A,
                            const unsigned short* __restrict__ feat,
                            const float* __restrict__ Wcat, const float* __restrict__ bias,
                            unsigned short* __restrict__ out_bf, float* __restrict__ out_f,
                            int N, int write_f32) {
    int n = blockIdx.x * TPB + threadIdx.x;
    if (n >= N) return;
    int c = blockIdx.y * 16;
    float acc[16];
#pragma unroll
    for (int j = 0; j < 16; ++j) acc[j] = 0.f;

    const uint4* ap = reinterpret_cast<const uint4*>(A + (size_t)n * 64);
#pragma unroll 4
    for (int b8 = 0; b8 < 16; ++b8) {
        uint4 q = ap[b8];
        unsigned int w[4] = {q.x, q.y, q.z, q.w};
        int ibase = b8 * 8;
#pragma unroll
        for (int h = 0; h < 4; ++h) {
            float flo = bf2f((unsigned short)(w[h] & 0xFFFF));
            float fhi = bf2f((unsigned short)(w[h] >> 16));
            const float* w0 = Wcat + (size_t)(ibase + 2 * h) * 64 + c;
            const float* w1 = w0 + 64;
#pragma unroll
            for (int j = 0; j < 16; ++j) acc[j] = fmaf(flo, w0[j], acc[j]);
#pragma unroll
            for (int j = 0; j < 16; ++j) acc[j] = fmaf(fhi, w1[j], acc[j]);
        }
    }
    const uint4* fp = reinterpret_cast<const uint4*>(feat + (size_t)n * 64);
#pragma unroll 4
    for (int b8 = 0; b8 < 8; ++b8) {
        uint4 q = fp[b8];
        unsigned int w[4] = {q.x, q.y, q.z, q.w};
        int ibase = 128 + b8 * 8;
#pragma unroll
        for (int h = 0; h < 4; ++h) {
            float flo = bf2f((unsigned short)(w[h] & 0xFFFF));
            float fhi = bf2f((unsigned short)(w[h] >> 16));
            const float* w0 = Wcat + (size_t)(ibase + 2 * h) * 64 + c;
            const float* w1 = w0 + 64;
#pragma unroll
            for (int j = 0; j < 16; ++j) acc[j] = fmaf(flo, w0[j], acc[j]);
#pragma unroll
            for (int j = 0; j < 16; ++j) acc[j] = fmaf(fhi, w1[j], acc[j]);
        }
    }
#pragma unroll
    for (int j = 0; j < 16; ++j) acc[j] = fmaxf(acc[j] + bias[c + j], 0.f);

    if (write_f32) {
        float* op = out_f + (size_t)n * 64 + c;
#pragma unroll
        for (int j4 = 0; j4 < 16; j4 += 4)
            *reinterpret_cast<float4*>(op + j4) =
                make_float4(acc[j4], acc[j4 + 1], acc[j4 + 2], acc[j4 + 3]);
    } else {
        unsigned short usx[16];
#pragma unroll
        for (int j = 0; j < 16; ++j) usx[j] = f2bf(acc[j]);
        uint4* op = reinterpret_cast<uint4*>(out_bf + (size_t)n * 64 + c);
        op[0] = reinterpret_cast<const uint4*>(usx)[0];
        op[1] = reinterpret_cast<const uint4*>(usx)[1];
    }
}

extern "C" void kernel_launch(void* const* d_in, const int* in_sizes, int n_in,
                              void* d_out, int out_size, void* d_ws, size_t ws_size,
                              hipStream_t stream) {
    const float* x   = (const float*)d_in[0];
    const int*   ei  = (const int*)d_in[1];      // int64 in reference -> int32 from harness
    const float* ea  = (const float*)d_in[2];
    const float* W1  = (const float*)d_in[3];
    const float* lw1 = (const float*)d_in[4];
    const float* b1  = (const float*)d_in[5];
    const float* W2  = (const float*)d_in[6];
    const float* lw2 = (const float*)d_in[7];
    const float* b2  = (const float*)d_in[8];

    const int N = in_sizes[0] / 64;
    const int E = in_sizes[1] / 2;

    char* p = (char*)d_ws;
    auto carve = [&](size_t bytes) -> void* {
        void* r = (void*)p;
        p += (bytes + 255) & ~(size_t)255;
        return r;
    };
    unsigned short* xb   = (unsigned short*)carve((size_t)N * 64 * 2);
    unsigned short* h    = (unsigned short*)carve((size_t)N * 64 * 2);
    unsigned int*   A    = (unsigned int*)carve((size_t)N * 64 * 4);
    float* Wcat     = (float*)carve(2 * 192 * 64 * 4);
    int*   counts   = (int*)carve((size_t)N * 4);
    int*   offsets  = (int*)carve((size_t)(N + 1) * 4);
    int*   bsum     = (int*)carve(256 * 4);
    unsigned int* combined = (unsigned int*)carve((size_t)E * 4);
    unsigned int* payload  = (unsigned int*)carve((size_t)E * 4);
    unsigned int* csr      = (unsigned int*)carve((size_t)E * 4);

    const int* src = ei;
    const int* dst = ei + E;

    int n4 = N * 64 / 4;
    cvt_bf16_kernel<<<(n4 + TPB - 1) / TPB, TPB, 0, stream>>>(x, (uint2*)xb, n4, counts, N);
    build_wcat2_kernel<<<(2 * 192 * 64 + TPB - 1) / TPB, TPB, 0, stream>>>(W1, lw1, W2, lw2, Wcat);

    int eBlocks = (E + TPB - 1) / TPB;
    count_kernel<<<eBlocks, TPB, 0, stream>>>(dst, src, ea, counts, combined, payload, E);

    int nscan = (N + 1023) / 1024;
    scan1_kernel<<<nscan, TPB, 0, stream>>>(counts, offsets, bsum, N);
    scan2_kernel<<<1, TPB, 0, stream>>>(bsum, nscan);
    scan3_kernel<<<nscan, TPB, 0, stream>>>(offsets, bsum, N, E);

    int nphases = (N + 16383) >> 14;
    fill_kernel<<<eBlocks, TPB, 0, stream>>>(combined, payload, offsets, csr, E, nphases);

    int aBlocks = (N + 3) / 4;          // 4 waves (nodes) per block
    dim3 ggrid((N + TPB - 1) / TPB, 4); // 4 out-col chunks of 16

    // Layer 1: agg on xb, then fused GEMM -> h (bf16)
    agg_kernel<<<aBlocks, TPB, 0, stream>>>(xb, offsets, csr, A, N);
    gemm_kernel<<<ggrid, TPB, 0, stream>>>(A, xb, Wcat, b1, h, nullptr, N, 0);
    // Layer 2: agg on h, then fused GEMM -> d_out (fp32)
    agg_kernel<<<aBlocks, TPB, 0, stream>>>(h, offsets, csr, A, N);
    gemm_kernel<<<ggrid, TPB, 0, stream>>>(A, h, Wcat + 192 * 64, b2, nullptr, (float*)d_out, N, 1);
}

// Round 5
// 203.915 us; speedup vs baseline: 2.5588x; 1.3298x over previous
//
#include <hip/hip_runtime.h>

#define TPB 256
// NOTE: packing assumes N < 131072 (17-bit node ids) and u in [0,1]. Holds for
// this problem (N=100000, edge_attr ~ U[0,1)).

typedef __attribute__((ext_vector_type(8))) short bf16x8;
typedef __attribute__((ext_vector_type(4))) float f32x4;

__device__ __forceinline__ float bf2f(unsigned short u) {
    unsigned int x = ((unsigned int)u) << 16;
    return __builtin_bit_cast(float, x);
}
__device__ __forceinline__ unsigned short f2bf(float f) {
    unsigned int u = __builtin_bit_cast(unsigned int, f);
    unsigned int r = u + 0x7FFFu + ((u >> 16) & 1u);   // round-to-nearest-even
    return (unsigned short)(r >> 16);
}

// fp32 -> packed bf16 (4 floats / thread); also zeroes counts[0..N).
__global__ void cvt_bf16_kernel(const float* __restrict__ in, uint2* __restrict__ out, int n4,
                                int* __restrict__ counts, int N) {
    int t = blockIdx.x * TPB + threadIdx.x;
    if (t < N) counts[t] = 0;
    if (t >= n4) return;
    float4 v = reinterpret_cast<const float4*>(in)[t];
    uint2 r;
    r.x = (unsigned int)f2bf(v.x) | ((unsigned int)f2bf(v.y) << 16);
    r.y = (unsigned int)f2bf(v.z) | ((unsigned int)f2bf(v.w) << 16);
    out[t] = r;
}

// Build MFMA A-operand fragment table (both layers), bf16.
// Logical weight matrix per layer: Wcat[192][64]; row k<128 -> W[k&1][k>>1][col]
// (interleaved W0/W1 to match A-buffer interleave), k>=128 -> lw[k-128][col].
// Fragment (kk,ct), lane l, elem j  =  Wcat[32*kk + 8*(l>>4) + j][16*ct + (l&15)].
// WA[layer*1536 + (kk*4+ct)*64 + l] = 8 bf16 (16 B).
__global__ void build_wa_kernel(const float* __restrict__ W1, const float* __restrict__ lw1,
                                const float* __restrict__ W2, const float* __restrict__ lw2,
                                bf16x8* __restrict__ WA) {
    int t = blockIdx.x * TPB + threadIdx.x;
    if (t >= 3072) return;
    int which = t / 1536;
    int rem = t - which * 1536;
    int fragid = rem >> 6;          // 0..23
    int lane = rem & 63;
    int kk = fragid >> 2, ct = fragid & 3;
    const float* W  = which ? W2  : W1;
    const float* lw = which ? lw2 : lw1;
    int col = ct * 16 + (lane & 15);
    int kbase = kk * 32 + (lane >> 4) * 8;
    short vals[8];
#pragma unroll
    for (int j = 0; j < 8; ++j) {
        int k = kbase + j;
        float v = (k < 128) ? W[(k & 1) * 4096 + (k >> 1) * 64 + col]
                            : lw[(k - 128) * 64 + col];
        vals[j] = (short)f2bf(v);
    }
    WA[t] = *reinterpret_cast<bf16x8*>(vals);
}

// counts + per-edge rank + precomputed packed payload (src | u15<<17).
__global__ void count_kernel(const int* __restrict__ dst, const int* __restrict__ src,
                             const float* __restrict__ u, int* __restrict__ counts,
                             unsigned int* __restrict__ combined,
                             unsigned int* __restrict__ payload, int E) {
    int e = blockIdx.x * TPB + threadIdx.x;
    if (e >= E) return;
    int d = dst[e];
    int r = atomicAdd(&counts[d], 1);
    combined[e] = (unsigned int)d | ((unsigned int)r << 17);
    unsigned int uq = (unsigned int)__float2int_rn(u[e] * 32767.f);
    payload[e] = (unsigned int)src[e] | (uq << 17);
}

// Block-level exclusive scan, 1024 elements per block (4 per thread).
__global__ void scan1_kernel(const int* __restrict__ counts, int* __restrict__ offsets,
                             int* __restrict__ bsum, int n) {
    __shared__ int s[TPB];
    int t = threadIdx.x;
    int base = blockIdx.x * 1024 + t * 4;
    int v[4];
#pragma unroll
    for (int q = 0; q < 4; ++q) v[q] = (base + q < n) ? counts[base + q] : 0;
    int tsum = v[0] + v[1] + v[2] + v[3];
    s[t] = tsum;
    __syncthreads();
    for (int off = 1; off < TPB; off <<= 1) {
        int x = (t >= off) ? s[t - off] : 0;
        __syncthreads();
        s[t] += x;
        __syncthreads();
    }
    int acc = s[t] - tsum;
#pragma unroll
    for (int q = 0; q < 4; ++q) {
        if (base + q < n) offsets[base + q] = acc;
        acc += v[q];
    }
    if (t == TPB - 1) bsum[blockIdx.x] = s[TPB - 1];
}

__global__ void scan2_kernel(int* __restrict__ bsum, int nblk) {
    __shared__ int s[TPB];
    int t = threadIdx.x;
    int v = (t < nblk) ? bsum[t] : 0;
    s[t] = v;
    __syncthreads();
    for (int off = 1; off < TPB; off <<= 1) {
        int x = (t >= off) ? s[t - off] : 0;
        __syncthreads();
        s[t] += x;
        __syncthreads();
    }
    if (t < nblk) bsum[t] = s[t] - v;
}

__global__ void scan3_kernel(int* __restrict__ offsets, const int* __restrict__ bsum,
                             int n, int E) {
    int base = blockIdx.x * 1024 + threadIdx.x * 4;
    int add = bsum[blockIdx.x];
#pragma unroll
    for (int q = 0; q < 4; ++q) {
        int idx = base + q;
        if (idx < n) offsets[idx] += add;
    }
    if (blockIdx.x == 0 && threadIdx.x == 0) offsets[n] = E;
}

// Phase-partitioned scatter: phase p handles dst in [p*16384, (p+1)*16384) so the
// live csr write window (~650 KB) stays L2-resident -> write combining works.
__global__ void fill_kernel(const unsigned int* __restrict__ combined,
                            const unsigned int* __restrict__ payload,
                            const int* __restrict__ offsets,
                            unsigned int* __restrict__ csr, int E, int nphases) {
    int stride = gridDim.x * TPB;
    for (int p = 0; p < nphases; ++p) {
        for (int e = blockIdx.x * TPB + threadIdx.x; e < E; e += stride) {
            unsigned int c = combined[e];
            int d = c & 0x1FFFF;
            if ((d >> 14) == p) {
                int pos = offsets[d] + (int)(c >> 17);
                csr[pos] = payload[e];
            }
        }
    }
}

// One wave per dst node; lane = channel. Gather bf16 feature rows; accumulate
// A0 = sum (1-u) feat[src], A1 = sum u feat[src] (exact for K=2); mean; store
// interleaved bf16 pairs (one uint per lane).
__global__ void agg_kernel(const unsigned short* __restrict__ feat,
                           const int* __restrict__ offsets,
                           const unsigned int* __restrict__ csr,
                           unsigned int* __restrict__ A, int N) {
    int gw = (blockIdx.x * TPB + threadIdx.x) >> 6;
    int lane = threadIdx.x & 63;
    if (gw >= N) return;
    int beg = offsets[gw], end = offsets[gw + 1];
    const float us = 1.f / 32767.f;
    float a0 = 0.f, a1 = 0.f;
    int j = beg;
    for (; j + 4 <= end; j += 4) {
        unsigned int c0 = csr[j], c1 = csr[j + 1], c2 = csr[j + 2], c3 = csr[j + 3];
        float f0 = bf2f(feat[(size_t)(c0 & 0x1FFFF) * 64 + lane]);
        float f1 = bf2f(feat[(size_t)(c1 & 0x1FFFF) * 64 + lane]);
        float f2 = bf2f(feat[(size_t)(c2 & 0x1FFFF) * 64 + lane]);
        float f3 = bf2f(feat[(size_t)(c3 & 0x1FFFF) * 64 + lane]);
        float u0 = (float)(c0 >> 17) * us, u1 = (float)(c1 >> 17) * us;
        float u2 = (float)(c2 >> 17) * us, u3 = (float)(c3 >> 17) * us;
        a0 = fmaf(f0, 1.f - u0, a0); a1 = fmaf(f0, u0, a1);
        a0 = fmaf(f1, 1.f - u1, a0); a1 = fmaf(f1, u1, a1);
        a0 = fmaf(f2, 1.f - u2, a0); a1 = fmaf(f2, u2, a1);
        a0 = fmaf(f3, 1.f - u3, a0); a1 = fmaf(f3, u3, a1);
    }
    for (; j < end; ++j) {
        unsigned int c0 = csr[j];
        float u0 = (float)(c0 >> 17) * us;
        float f0 = bf2f(feat[(size_t)(c0 & 0x1FFFF) * 64 + lane]);
        a0 = fmaf(f0, 1.f - u0, a0); a1 = fmaf(f0, u0, a1);
    }
    int cnt = end - beg;
    float inv = 1.f / (float)(cnt > 0 ? cnt : 1);
    unsigned int packed = (unsigned int)f2bf(a0 * inv) | ((unsigned int)f2bf(a1 * inv) << 16);
    A[(size_t)gw * 64 + lane] = packed;
}

// MFMA GEMM: out[n][0..63] = relu(q[n]·Wcat + b), q = [A(128) | feat(64)] bf16.
// Operands swapped: A-op = weight fragments (WA), B-op = node q-rows.
// Wave handles 16 nodes; 4 col-tiles x 6 k-steps = 24 MFMAs.
// D layout: col(lane&15)=node, row(4*(lane>>4)+reg)=out-col -> 4 contiguous
// out-cols per acc -> packed stores, no LDS.
__global__ void gemm_mfma_kernel(const unsigned int* __restrict__ A,
                                 const unsigned short* __restrict__ feat,
                                 const bf16x8* __restrict__ WA,
                                 const float* __restrict__ bias,
                                 unsigned short* __restrict__ out_bf,
                                 float* __restrict__ out_f,
                                 int N, int write_f32) {
    int w = threadIdx.x >> 6, lane = threadIdx.x & 63;
    int node = blockIdx.x * 64 + w * 16 + (lane & 15);
    int nc = min(node, N - 1);
    int kq = lane >> 4;                         // k-quad 0..3
    const char* arow = (const char*)A + (size_t)nc * 256 + kq * 16;
    const char* frow = (const char*)feat + (size_t)nc * 128 + kq * 16;
    bf16x8 bq[6];
    bq[0] = *(const bf16x8*)(arow);
    bq[1] = *(const bf16x8*)(arow + 64);
    bq[2] = *(const bf16x8*)(arow + 128);
    bq[3] = *(const bf16x8*)(arow + 192);
    bq[4] = *(const bf16x8*)(frow);
    bq[5] = *(const bf16x8*)(frow + 64);

    f32x4 acc0 = {0.f, 0.f, 0.f, 0.f}, acc1 = acc0, acc2 = acc0, acc3 = acc0;
#pragma unroll
    for (int kk = 0; kk < 6; ++kk) {
        bf16x8 b = bq[kk];
        acc0 = __builtin_amdgcn_mfma_f32_16x16x32_bf16(WA[(kk * 4 + 0) * 64 + lane], b, acc0, 0, 0, 0);
        acc1 = __builtin_amdgcn_mfma_f32_16x16x32_bf16(WA[(kk * 4 + 1) * 64 + lane], b, acc1, 0, 0, 0);
        acc2 = __builtin_amdgcn_mfma_f32_16x16x32_bf16(WA[(kk * 4 + 2) * 64 + lane], b, acc2, 0, 0, 0);
        acc3 = __builtin_amdgcn_mfma_f32_16x16x32_bf16(WA[(kk * 4 + 3) * 64 + lane], b, acc3, 0, 0, 0);
    }
    if (node >= N) return;

    f32x4 accs[4] = {acc0, acc1, acc2, acc3};
    int cb_hi = 4 * kq;
#pragma unroll
    for (int ct = 0; ct < 4; ++ct) {
        int cb = ct * 16 + cb_hi;               // out-col base (multiple of 4)
        float r0 = fmaxf(accs[ct][0] + bias[cb + 0], 0.f);
        float r1 = fmaxf(accs[ct][1] + bias[cb + 1], 0.f);
        float r2 = fmaxf(accs[ct][2] + bias[cb + 2], 0.f);
        float r3 = fmaxf(accs[ct][3] + bias[cb + 3], 0.f);
        if (write_f32) {
            *reinterpret_cast<float4*>(out_f + (size_t)node * 64 + cb) =
                make_float4(r0, r1, r2, r3);
        } else {
            uint2 pk;
            pk.x = (unsigned int)f2bf(r0) | ((unsigned int)f2bf(r1) << 16);
            pk.y = (unsigned int)f2bf(r2) | ((unsigned int)f2bf(r3) << 16);
            *reinterpret_cast<uint2*>(out_bf + (size_t)node * 64 + cb) = pk;
        }
    }
}

extern "C" void kernel_launch(void* const* d_in, const int* in_sizes, int n_in,
                              void* d_out, int out_size, void* d_ws, size_t ws_size,
                              hipStream_t stream) {
    const float* x   = (const float*)d_in[0];
    const int*   ei  = (const int*)d_in[1];      // int64 in reference -> int32 from harness
    const float* ea  = (const float*)d_in[2];
    const float* W1  = (const float*)d_in[3];
    const float* lw1 = (const float*)d_in[4];
    const float* b1  = (const float*)d_in[5];
    const float* W2  = (const float*)d_in[6];
    const float* lw2 = (const float*)d_in[7];
    const float* b2  = (const float*)d_in[8];

    const int N = in_sizes[0] / 64;
    const int E = in_sizes[1] / 2;

    char* p = (char*)d_ws;
    auto carve = [&](size_t bytes) -> void* {
        void* r = (void*)p;
        p += (bytes + 255) & ~(size_t)255;
        return r;
    };
    unsigned short* xb   = (unsigned short*)carve((size_t)N * 64 * 2);
    unsigned short* h    = (unsigned short*)carve((size_t)N * 64 * 2);
    unsigned int*   A    = (unsigned int*)carve((size_t)N * 64 * 4);
    bf16x8* WA      = (bf16x8*)carve(3072 * 16);
    int*   counts   = (int*)carve((size_t)N * 4);
    int*   offsets  = (int*)carve((size_t)(N + 1) * 4);
    int*   bsum     = (int*)carve(256 * 4);
    unsigned int* combined = (unsigned int*)carve((size_t)E * 4);
    unsigned int* payload  = (unsigned int*)carve((size_t)E * 4);
    unsigned int* csr      = (unsigned int*)carve((size_t)E * 4);

    const int* src = ei;
    const int* dst = ei + E;

    int n4 = N * 64 / 4;
    cvt_bf16_kernel<<<(n4 + TPB - 1) / TPB, TPB, 0, stream>>>(x, (uint2*)xb, n4, counts, N);
    build_wa_kernel<<<(3072 + TPB - 1) / TPB, TPB, 0, stream>>>(W1, lw1, W2, lw2, WA);

    int eBlocks = (E + TPB - 1) / TPB;
    count_kernel<<<eBlocks, TPB, 0, stream>>>(dst, src, ea, counts, combined, payload, E);

    int nscan = (N + 1023) / 1024;
    scan1_kernel<<<nscan, TPB, 0, stream>>>(counts, offsets, bsum, N);
    scan2_kernel<<<1, TPB, 0, stream>>>(bsum, nscan);
    scan3_kernel<<<nscan, TPB, 0, stream>>>(offsets, bsum, N, E);

    int nphases = (N + 16383) >> 14;
    fill_kernel<<<eBlocks, TPB, 0, stream>>>(combined, payload, offsets, csr, E, nphases);

    int aBlocks = (N + 3) / 4;            // 4 waves (nodes) per block
    int gBlocks = (N + 63) / 64;          // 4 waves x 16 nodes per block

    // Layer 1: agg on xb, then MFMA GEMM -> h (bf16)
    agg_kernel<<<aBlocks, TPB, 0, stream>>>(xb, offsets, csr, A, N);
    gemm_mfma_kernel<<<gBlocks, TPB, 0, stream>>>(A, xb, WA, b1, h, nullptr, N, 0);
    // Layer 2: agg on h, then MFMA GEMM -> d_out (fp32)
    agg_kernel<<<aBlocks, TPB, 0, stream>>>(h, offsets, csr, A, N);
    gemm_mfma_kernel<<<gBlocks, TPB, 0, stream>>>(A, h, WA + 1536, b2, nullptr, (float*)d_out, N, 1);
}

// Round 6
// 197.576 us; speedup vs baseline: 2.6409x; 1.0321x over previous
//
#include <hip/hip_runtime.h>

#define TPB 256
// NOTE: packing assumes N < 131072 (17-bit node ids) and u in [0,1]. Holds for
// this problem (N=100000, edge_attr ~ U[0,1)).

typedef __attribute__((ext_vector_type(8))) short bf16x8;
typedef __attribute__((ext_vector_type(4))) float f32x4;

__device__ __forceinline__ float bf2f(unsigned short u) {
    unsigned int x = ((unsigned int)u) << 16;
    return __builtin_bit_cast(float, x);
}
__device__ __forceinline__ unsigned short f2bf(float f) {
    unsigned int u = __builtin_bit_cast(unsigned int, f);
    unsigned int r = u + 0x7FFFu + ((u >> 16) & 1u);   // round-to-nearest-even
    return (unsigned short)(r >> 16);
}

// fp32 -> packed bf16 (4 floats / thread); also zeroes counts[0..N).
__global__ void cvt_bf16_kernel(const float* __restrict__ in, uint2* __restrict__ out, int n4,
                                int* __restrict__ counts, int N) {
    int t = blockIdx.x * TPB + threadIdx.x;
    if (t < N) counts[t] = 0;
    if (t >= n4) return;
    float4 v = reinterpret_cast<const float4*>(in)[t];
    uint2 r;
    r.x = (unsigned int)f2bf(v.x) | ((unsigned int)f2bf(v.y) << 16);
    r.y = (unsigned int)f2bf(v.z) | ((unsigned int)f2bf(v.w) << 16);
    out[t] = r;
}

// Build MFMA A-operand fragment table (both layers), bf16.
// Fragment (kk,ct), lane l, elem j  =  Wcat[32*kk + 8*(l>>4) + j][16*ct + (l&15)],
// Wcat row k<128 -> W[k&1][k>>1][col] (interleaved W0/W1), k>=128 -> lw[k-128][col].
__global__ void build_wa_kernel(const float* __restrict__ W1, const float* __restrict__ lw1,
                                const float* __restrict__ W2, const float* __restrict__ lw2,
                                bf16x8* __restrict__ WA) {
    int t = blockIdx.x * TPB + threadIdx.x;
    if (t >= 3072) return;
    int which = t / 1536;
    int rem = t - which * 1536;
    int fragid = rem >> 6;          // 0..23
    int lane = rem & 63;
    int kk = fragid >> 2, ct = fragid & 3;
    const float* W  = which ? W2  : W1;
    const float* lw = which ? lw2 : lw1;
    int col = ct * 16 + (lane & 15);
    int kbase = kk * 32 + (lane >> 4) * 8;
    short vals[8];
#pragma unroll
    for (int j = 0; j < 8; ++j) {
        int k = kbase + j;
        float v = (k < 128) ? W[(k & 1) * 4096 + (k >> 1) * 64 + col]
                            : lw[(k - 128) * 64 + col];
        vals[j] = (short)f2bf(v);
    }
    WA[t] = *reinterpret_cast<bf16x8*>(vals);
}

// counts + per-edge rank + precomputed packed payload (src | u15<<17).
__global__ void count_kernel(const int* __restrict__ dst, const int* __restrict__ src,
                             const float* __restrict__ u, int* __restrict__ counts,
                             unsigned int* __restrict__ combined,
                             unsigned int* __restrict__ payload, int E) {
    int e = blockIdx.x * TPB + threadIdx.x;
    if (e >= E) return;
    int d = dst[e];
    int r = atomicAdd(&counts[d], 1);
    combined[e] = (unsigned int)d | ((unsigned int)r << 17);
    unsigned int uq = (unsigned int)__float2int_rn(u[e] * 32767.f);
    payload[e] = (unsigned int)src[e] | (uq << 17);
}

// Block-level exclusive scan, 1024 elements per block (4 per thread).
__global__ void scan1_kernel(const int* __restrict__ counts, int* __restrict__ offsets,
                             int* __restrict__ bsum, int n) {
    __shared__ int s[TPB];
    int t = threadIdx.x;
    int base = blockIdx.x * 1024 + t * 4;
    int v[4];
#pragma unroll
    for (int q = 0; q < 4; ++q) v[q] = (base + q < n) ? counts[base + q] : 0;
    int tsum = v[0] + v[1] + v[2] + v[3];
    s[t] = tsum;
    __syncthreads();
    for (int off = 1; off < TPB; off <<= 1) {
        int x = (t >= off) ? s[t - off] : 0;
        __syncthreads();
        s[t] += x;
        __syncthreads();
    }
    int acc = s[t] - tsum;
#pragma unroll
    for (int q = 0; q < 4; ++q) {
        if (base + q < n) offsets[base + q] = acc;
        acc += v[q];
    }
    if (t == TPB - 1) bsum[blockIdx.x] = s[TPB - 1];
}

__global__ void scan2_kernel(int* __restrict__ bsum, int nblk) {
    __shared__ int s[TPB];
    int t = threadIdx.x;
    int v = (t < nblk) ? bsum[t] : 0;
    s[t] = v;
    __syncthreads();
    for (int off = 1; off < TPB; off <<= 1) {
        int x = (t >= off) ? s[t - off] : 0;
        __syncthreads();
        s[t] += x;
        __syncthreads();
    }
    if (t < nblk) bsum[t] = s[t] - v;
}

__global__ void scan3_kernel(int* __restrict__ offsets, const int* __restrict__ bsum,
                             int n, int E) {
    int base = blockIdx.x * 1024 + threadIdx.x * 4;
    int add = bsum[blockIdx.x];
#pragma unroll
    for (int q = 0; q < 4; ++q) {
        int idx = base + q;
        if (idx < n) offsets[idx] += add;
    }
    if (blockIdx.x == 0 && threadIdx.x == 0) offsets[n] = E;
}

// Phase-partitioned scatter: phase p handles dst in [p*32768, (p+1)*32768) so the
// live csr write window (~1.3 MB) stays L2-resident -> write combining works.
__global__ void fill_kernel(const unsigned int* __restrict__ combined,
                            const unsigned int* __restrict__ payload,
                            const int* __restrict__ offsets,
                            unsigned int* __restrict__ csr, int E, int nphases) {
    int stride = gridDim.x * TPB;
    for (int p = 0; p < nphases; ++p) {
        for (int e = blockIdx.x * TPB + threadIdx.x; e < E; e += stride) {
            unsigned int c = combined[e];
            int d = c & 0x1FFFF;
            if ((d >> 15) == p) {
                int pos = offsets[d] + (int)(c >> 17);
                csr[pos] = payload[e];
            }
        }
    }
}

// One wave per dst node; TWO edges per iteration (half-wave per edge, 32 lanes,
// 4 B = 2 packed bf16 channels per lane). Accumulate a0 = sum (1-u) feat[src],
// a1 = sum u feat[src]; combine halves via shfl_xor; mean; store interleaved
// bf16 pairs (uint2 per lane, half 0 only).
__global__ void agg_kernel(const unsigned int* __restrict__ featu,
                           const int* __restrict__ offsets,
                           const unsigned int* __restrict__ csr,
                           unsigned int* __restrict__ A, int N) {
    int gw = (blockIdx.x * TPB + threadIdx.x) >> 6;
    int lane = threadIdx.x & 63;
    if (gw >= N) return;
    int half = lane >> 5, sub = lane & 31;
    int beg = offsets[gw], end = offsets[gw + 1];
    const float us = 1.f / 32767.f;
    float a0x = 0.f, a1x = 0.f, a0y = 0.f, a1y = 0.f;  // x = ch 2*sub, y = ch 2*sub+1
    int j = beg;
    for (; j + 4 <= end; j += 4) {
        unsigned int ca = csr[j + half];
        unsigned int cb = csr[j + 2 + half];
        unsigned int fa = featu[(size_t)(ca & 0x1FFFF) * 32 + sub];
        unsigned int fb = featu[(size_t)(cb & 0x1FFFF) * 32 + sub];
        float ua = (float)(ca >> 17) * us, ub = (float)(cb >> 17) * us;
        float fax = bf2f((unsigned short)fa), fay = bf2f((unsigned short)(fa >> 16));
        float fbx = bf2f((unsigned short)fb), fby = bf2f((unsigned short)(fb >> 16));
        a0x = fmaf(fax, 1.f - ua, a0x); a1x = fmaf(fax, ua, a1x);
        a0y = fmaf(fay, 1.f - ua, a0y); a1y = fmaf(fay, ua, a1y);
        a0x = fmaf(fbx, 1.f - ub, a0x); a1x = fmaf(fbx, ub, a1x);
        a0y = fmaf(fby, 1.f - ub, a0y); a1y = fmaf(fby, ub, a1y);
    }
    for (; j + 2 <= end; j += 2) {
        unsigned int ca = csr[j + half];
        unsigned int fa = featu[(size_t)(ca & 0x1FFFF) * 32 + sub];
        float ua = (float)(ca >> 17) * us;
        float fax = bf2f((unsigned short)fa), fay = bf2f((unsigned short)(fa >> 16));
        a0x = fmaf(fax, 1.f - ua, a0x); a1x = fmaf(fax, ua, a1x);
        a0y = fmaf(fay, 1.f - ua, a0y); a1y = fmaf(fay, ua, a1y);
    }
    if (j < end && half == 0) {       // one leftover edge, half 0 processes it
        unsigned int ca = csr[j];
        unsigned int fa = featu[(size_t)(ca & 0x1FFFF) * 32 + sub];
        float ua = (float)(ca >> 17) * us;
        float fax = bf2f((unsigned short)fa), fay = bf2f((unsigned short)(fa >> 16));
        a0x = fmaf(fax, 1.f - ua, a0x); a1x = fmaf(fax, ua, a1x);
        a0y = fmaf(fay, 1.f - ua, a0y); a1y = fmaf(fay, ua, a1y);
    }
    a0x += __shfl_xor(a0x, 32); a1x += __shfl_xor(a1x, 32);
    a0y += __shfl_xor(a0y, 32); a1y += __shfl_xor(a1y, 32);
    int cnt = end - beg;
    float inv = 1.f / (float)(cnt > 0 ? cnt : 1);
    if (half == 0) {
        uint2 pk;
        pk.x = (unsigned int)f2bf(a0x * inv) | ((unsigned int)f2bf(a1x * inv) << 16);
        pk.y = (unsigned int)f2bf(a0y * inv) | ((unsigned int)f2bf(a1y * inv) << 16);
        *reinterpret_cast<uint2*>(A + (size_t)gw * 64 + sub * 2) = pk;
    }
}

// MFMA GEMM: out[n][0..63] = relu(q[n]·Wcat + b), q = [A(128) | feat(64)] bf16.
// A-op = weight fragments (WA), B-op = node q-rows. Wave = 16 nodes, 24 MFMAs.
__global__ void gemm_mfma_kernel(const unsigned int* __restrict__ A,
                                 const unsigned short* __restrict__ feat,
                                 const bf16x8* __restrict__ WA,
                                 const float* __restrict__ bias,
                                 unsigned short* __restrict__ out_bf,
                                 float* __restrict__ out_f,
                                 int N, int write_f32) {
    int w = threadIdx.x >> 6, lane = threadIdx.x & 63;
    int node = blockIdx.x * 64 + w * 16 + (lane & 15);
    int nc = min(node, N - 1);
    int kq = lane >> 4;                         // k-quad 0..3
    const char* arow = (const char*)A + (size_t)nc * 256 + kq * 16;
    const char* frow = (const char*)feat + (size_t)nc * 128 + kq * 16;
    bf16x8 bq[6];
    bq[0] = *(const bf16x8*)(arow);
    bq[1] = *(const bf16x8*)(arow + 64);
    bq[2] = *(const bf16x8*)(arow + 128);
    bq[3] = *(const bf16x8*)(arow + 192);
    bq[4] = *(const bf16x8*)(frow);
    bq[5] = *(const bf16x8*)(frow + 64);

    f32x4 acc0 = {0.f, 0.f, 0.f, 0.f}, acc1 = acc0, acc2 = acc0, acc3 = acc0;
#pragma unroll
    for (int kk = 0; kk < 6; ++kk) {
        bf16x8 b = bq[kk];
        acc0 = __builtin_amdgcn_mfma_f32_16x16x32_bf16(WA[(kk * 4 + 0) * 64 + lane], b, acc0, 0, 0, 0);
        acc1 = __builtin_amdgcn_mfma_f32_16x16x32_bf16(WA[(kk * 4 + 1) * 64 + lane], b, acc1, 0, 0, 0);
        acc2 = __builtin_amdgcn_mfma_f32_16x16x32_bf16(WA[(kk * 4 + 2) * 64 + lane], b, acc2, 0, 0, 0);
        acc3 = __builtin_amdgcn_mfma_f32_16x16x32_bf16(WA[(kk * 4 + 3) * 64 + lane], b, acc3, 0, 0, 0);
    }
    if (node >= N) return;

    f32x4 accs[4] = {acc0, acc1, acc2, acc3};
    int cb_hi = 4 * kq;
#pragma unroll
    for (int ct = 0; ct < 4; ++ct) {
        int cb = ct * 16 + cb_hi;               // out-col base (multiple of 4)
        float r0 = fmaxf(accs[ct][0] + bias[cb + 0], 0.f);
        float r1 = fmaxf(accs[ct][1] + bias[cb + 1], 0.f);
        float r2 = fmaxf(accs[ct][2] + bias[cb + 2], 0.f);
        float r3 = fmaxf(accs[ct][3] + bias[cb + 3], 0.f);
        if (write_f32) {
            *reinterpret_cast<float4*>(out_f + (size_t)node * 64 + cb) =
                make_float4(r0, r1, r2, r3);
        } else {
            uint2 pk;
            pk.x = (unsigned int)f2bf(r0) | ((unsigned int)f2bf(r1) << 16);
            pk.y = (unsigned int)f2bf(r2) | ((unsigned int)f2bf(r3) << 16);
            *reinterpret_cast<uint2*>(out_bf + (size_t)node * 64 + cb) = pk;
        }
    }
}

extern "C" void kernel_launch(void* const* d_in, const int* in_sizes, int n_in,
                              void* d_out, int out_size, void* d_ws, size_t ws_size,
                              hipStream_t stream) {
    const float* x   = (const float*)d_in[0];
    const int*   ei  = (const int*)d_in[1];      // int64 in reference -> int32 from harness
    const float* ea  = (const float*)d_in[2];
    const float* W1  = (const float*)d_in[3];
    const float* lw1 = (const float*)d_in[4];
    const float* b1  = (const float*)d_in[5];
    const float* W2  = (const float*)d_in[6];
    const float* lw2 = (const float*)d_in[7];
    const float* b2  = (const float*)d_in[8];

    const int N = in_sizes[0] / 64;
    const int E = in_sizes[1] / 2;

    char* p = (char*)d_ws;
    auto carve = [&](size_t bytes) -> void* {
        void* r = (void*)p;
        p += (bytes + 255) & ~(size_t)255;
        return r;
    };
    unsigned short* xb   = (unsigned short*)carve((size_t)N * 64 * 2);
    unsigned short* h    = (unsigned short*)carve((size_t)N * 64 * 2);
    unsigned int*   A    = (unsigned int*)carve((size_t)N * 64 * 4);
    bf16x8* WA      = (bf16x8*)carve(3072 * 16);
    int*   counts   = (int*)carve((size_t)N * 4);
    int*   offsets  = (int*)carve((size_t)(N + 1) * 4);
    int*   bsum     = (int*)carve(256 * 4);
    unsigned int* combined = (unsigned int*)carve((size_t)E * 4);
    unsigned int* payload  = (unsigned int*)carve((size_t)E * 4);
    unsigned int* csr      = (unsigned int*)carve((size_t)E * 4);

    const int* src = ei;
    const int* dst = ei + E;

    int n4 = N * 64 / 4;
    cvt_bf16_kernel<<<(n4 + TPB - 1) / TPB, TPB, 0, stream>>>(x, (uint2*)xb, n4, counts, N);
    build_wa_kernel<<<(3072 + TPB - 1) / TPB, TPB, 0, stream>>>(W1, lw1, W2, lw2, WA);

    int eBlocks = (E + TPB - 1) / TPB;
    count_kernel<<<eBlocks, TPB, 0, stream>>>(dst, src, ea, counts, combined, payload, E);

    int nscan = (N + 1023) / 1024;
    scan1_kernel<<<nscan, TPB, 0, stream>>>(counts, offsets, bsum, N);
    scan2_kernel<<<1, TPB, 0, stream>>>(bsum, nscan);
    scan3_kernel<<<nscan, TPB, 0, stream>>>(offsets, bsum, N, E);

    int nphases = (N + 32767) >> 15;
    fill_kernel<<<eBlocks, TPB, 0, stream>>>(combined, payload, offsets, csr, E, nphases);

    int aBlocks = (N + 3) / 4;            // 4 waves (nodes) per block
    int gBlocks = (N + 63) / 64;          // 4 waves x 16 nodes per block

    // Layer 1: agg on xb, then MFMA GEMM -> h (bf16)
    agg_kernel<<<aBlocks, TPB, 0, stream>>>((const unsigned int*)xb, offsets, csr, A, N);
    gemm_mfma_kernel<<<gBlocks, TPB, 0, stream>>>(A, xb, WA, b1, h, nullptr, N, 0);
    // Layer 2: agg on h, then MFMA GEMM -> d_out (fp32)
    agg_kernel<<<aBlocks, TPB, 0, stream>>>((const unsigned int*)h, offsets, csr, A, N);
    gemm_mfma_kernel<<<gBlocks, TPB, 0, stream>>>(A, h, WA + 1536, b2, nullptr, (float*)d_out, N, 1);
}

// Round 7
// 181.196 us; speedup vs baseline: 2.8796x; 1.0904x over previous
//
#include <hip/hip_runtime.h>

#define TPB 256
// NOTE: packing assumes N < 131072 (17-bit node ids) and u in [0,1]. Holds for
// this problem (N=100000, edge_attr ~ U[0,1)).

typedef __attribute__((ext_vector_type(8))) short bf16x8;
typedef __attribute__((ext_vector_type(4))) float f32x4;

__device__ __forceinline__ float bf2f(unsigned short u) {
    unsigned int x = ((unsigned int)u) << 16;
    return __builtin_bit_cast(float, x);
}
__device__ __forceinline__ unsigned short f2bf(float f) {
    unsigned int u = __builtin_bit_cast(unsigned int, f);
    unsigned int r = u + 0x7FFFu + ((u >> 16) & 1u);   // round-to-nearest-even
    return (unsigned short)(r >> 16);
}

// fp32 -> packed bf16 (4 floats / thread); also zeroes counts[0..N).
__global__ void cvt_bf16_kernel(const float* __restrict__ in, uint2* __restrict__ out, int n4,
                                int* __restrict__ counts, int N) {
    int t = blockIdx.x * TPB + threadIdx.x;
    if (t < N) counts[t] = 0;
    if (t >= n4) return;
    float4 v = reinterpret_cast<const float4*>(in)[t];
    uint2 r;
    r.x = (unsigned int)f2bf(v.x) | ((unsigned int)f2bf(v.y) << 16);
    r.y = (unsigned int)f2bf(v.z) | ((unsigned int)f2bf(v.w) << 16);
    out[t] = r;
}

// Build MFMA A-operand fragment table (both layers), bf16.
// Fragment (kk,ct), lane l, elem j  =  Wcat[32*kk + 8*(l>>4) + j][16*ct + (l&15)],
// Wcat row k<128 -> W[k&1][k>>1][col] (interleaved W0/W1), k>=128 -> lw[k-128][col].
__global__ void build_wa_kernel(const float* __restrict__ W1, const float* __restrict__ lw1,
                                const float* __restrict__ W2, const float* __restrict__ lw2,
                                bf16x8* __restrict__ WA) {
    int t = blockIdx.x * TPB + threadIdx.x;
    if (t >= 3072) return;
    int which = t / 1536;
    int rem = t - which * 1536;
    int fragid = rem >> 6;          // 0..23
    int lane = rem & 63;
    int kk = fragid >> 2, ct = fragid & 3;
    const float* W  = which ? W2  : W1;
    const float* lw = which ? lw2 : lw1;
    int col = ct * 16 + (lane & 15);
    int kbase = kk * 32 + (lane >> 4) * 8;
    short vals[8];
#pragma unroll
    for (int j = 0; j < 8; ++j) {
        int k = kbase + j;
        float v = (k < 128) ? W[(k & 1) * 4096 + (k >> 1) * 64 + col]
                            : lw[(k - 128) * 64 + col];
        vals[j] = (short)f2bf(v);
    }
    WA[t] = *reinterpret_cast<bf16x8*>(vals);
}

// counts + per-edge rank + fused packed record {dst|rank<<17, src|u15<<17}.
__global__ void count_kernel(const int* __restrict__ dst, const int* __restrict__ src,
                             const float* __restrict__ u, int* __restrict__ counts,
                             uint2* __restrict__ cp, int E) {
    int e = blockIdx.x * TPB + threadIdx.x;
    if (e >= E) return;
    int d = dst[e];
    int r = atomicAdd(&counts[d], 1);
    unsigned int uq = (unsigned int)__float2int_rn(u[e] * 32767.f);
    cp[e] = make_uint2((unsigned int)d | ((unsigned int)r << 17),
                       (unsigned int)src[e] | (uq << 17));
}

// Block-level exclusive scan, 1024 elements per block (4 per thread).
__global__ void scan1_kernel(const int* __restrict__ counts, int* __restrict__ offsets,
                             int* __restrict__ bsum, int n) {
    __shared__ int s[TPB];
    int t = threadIdx.x;
    int base = blockIdx.x * 1024 + t * 4;
    int v[4];
#pragma unroll
    for (int q = 0; q < 4; ++q) v[q] = (base + q < n) ? counts[base + q] : 0;
    int tsum = v[0] + v[1] + v[2] + v[3];
    s[t] = tsum;
    __syncthreads();
    for (int off = 1; off < TPB; off <<= 1) {
        int x = (t >= off) ? s[t - off] : 0;
        __syncthreads();
        s[t] += x;
        __syncthreads();
    }
    int acc = s[t] - tsum;
#pragma unroll
    for (int q = 0; q < 4; ++q) {
        if (base + q < n) offsets[base + q] = acc;
        acc += v[q];
    }
    if (t == TPB - 1) bsum[blockIdx.x] = s[TPB - 1];
}

__global__ void scan2_kernel(int* __restrict__ bsum, int nblk) {
    __shared__ int s[TPB];
    int t = threadIdx.x;
    int v = (t < nblk) ? bsum[t] : 0;
    s[t] = v;
    __syncthreads();
    for (int off = 1; off < TPB; off <<= 1) {
        int x = (t >= off) ? s[t - off] : 0;
        __syncthreads();
        s[t] += x;
        __syncthreads();
    }
    if (t < nblk) bsum[t] = s[t] - v;
}

__global__ void scan3_kernel(int* __restrict__ offsets, const int* __restrict__ bsum,
                             int n, int E) {
    int base = blockIdx.x * 1024 + threadIdx.x * 4;
    int add = bsum[blockIdx.x];
#pragma unroll
    for (int q = 0; q < 4; ++q) {
        int idx = base + q;
        if (idx < n) offsets[idx] += add;
    }
    if (blockIdx.x == 0 && threadIdx.x == 0) offsets[n] = E;
}

// Phase-partitioned scatter: phase p handles dst in [p*65536, (p+1)*65536) so the
// live csr write window (<=2.6 MB) stays L2-resident -> write combining works.
__global__ void fill_kernel(const uint2* __restrict__ cp,
                            const int* __restrict__ offsets,
                            unsigned int* __restrict__ csr, int E, int nphases) {
    int stride = gridDim.x * TPB;
    for (int p = 0; p < nphases; ++p) {
        for (int e = blockIdx.x * TPB + threadIdx.x; e < E; e += stride) {
            uint2 r = cp[e];
            int d = r.x & 0x1FFFF;
            if ((d >> 16) == p) {
                int pos = offsets[d] + (int)(r.x >> 17);
                csr[pos] = r.y;
            }
        }
    }
}

// One wave per dst node. All CSR records for the node preloaded into lanes with
// ONE vector load; edge records then come from registers (ds_bpermute), so the
// loop has a single memory hop (the feature gather). Two edges per pair-step
// (half-wave each, 4 B = 2 channels/lane), 4 pair-steps unrolled -> 4
// independent gathers in flight. Fallback loop for degree > 64 (never taken
// for Poisson(10) but correct).
__global__ void agg_kernel(const unsigned int* __restrict__ featu,
                           const int* __restrict__ offsets,
                           const unsigned int* __restrict__ csr,
                           unsigned int* __restrict__ A, int N) {
    int gw = (blockIdx.x * TPB + threadIdx.x) >> 6;
    int lane = threadIdx.x & 63;
    if (gw >= N) return;
    int beg = offsets[gw], end = offsets[gw + 1];
    int cnt = end - beg;
    int half = lane >> 5, sub = lane & 31;
    const float us = 1.f / 32767.f;

    unsigned int cw = (lane < cnt) ? csr[beg + lane] : 0u;

    float a0x = 0.f, a1x = 0.f, a0y = 0.f, a1y = 0.f;  // x = ch 2*sub, y = ch 2*sub+1
    int npre = cnt < 64 ? cnt : 64;
    int npair = npre >> 1;
    int j = 0;

#define PAIR_MATH(C, F)                                                        \
    {                                                                          \
        float uu = (float)((C) >> 17) * us;                                    \
        float w0 = 1.f - uu;                                                   \
        float fx = bf2f((unsigned short)(F));                                  \
        float fy = bf2f((unsigned short)((F) >> 16));                          \
        a0x = fmaf(fx, w0, a0x); a1x = fmaf(fx, uu, a1x);                      \
        a0y = fmaf(fy, w0, a0y); a1y = fmaf(fy, uu, a1y);                      \
    }

    for (; j + 4 <= npair; j += 4) {
        unsigned int c0 = __shfl(cw, 2 * j     + half);
        unsigned int c1 = __shfl(cw, 2 * j + 2 + half);
        unsigned int c2 = __shfl(cw, 2 * j + 4 + half);
        unsigned int c3 = __shfl(cw, 2 * j + 6 + half);
        unsigned int f0 = featu[(size_t)(c0 & 0x1FFFF) * 32 + sub];
        unsigned int f1 = featu[(size_t)(c1 & 0x1FFFF) * 32 + sub];
        unsigned int f2 = featu[(size_t)(c2 & 0x1FFFF) * 32 + sub];
        unsigned int f3 = featu[(size_t)(c3 & 0x1FFFF) * 32 + sub];
        PAIR_MATH(c0, f0); PAIR_MATH(c1, f1); PAIR_MATH(c2, f2); PAIR_MATH(c3, f3);
    }
    for (; j < npair; ++j) {
        unsigned int c0 = __shfl(cw, 2 * j + half);
        unsigned int f0 = featu[(size_t)(c0 & 0x1FFFF) * 32 + sub];
        PAIR_MATH(c0, f0);
    }
    if (npre & 1) {                 // leftover edge: half 0 contributes, half 1 zero-weighted
        unsigned int c0 = __shfl(cw, npre - 1);
        unsigned int f0 = featu[(size_t)(c0 & 0x1FFFF) * 32 + sub];
        float uu = (float)(c0 >> 17) * us;
        float w0 = (half == 0) ? 1.f - uu : 0.f;
        float w1 = (half == 0) ? uu : 0.f;
        float fx = bf2f((unsigned short)f0);
        float fy = bf2f((unsigned short)(f0 >> 16));
        a0x = fmaf(fx, w0, a0x); a1x = fmaf(fx, w1, a1x);
        a0y = fmaf(fy, w0, a0y); a1y = fmaf(fy, w1, a1y);
    }
    // degree > 64 fallback (correctness only; effectively never taken)
    for (int jj = 64 + half; jj < cnt; jj += 2) {
        unsigned int c0 = csr[beg + jj];
        unsigned int f0 = featu[(size_t)(c0 & 0x1FFFF) * 32 + sub];
        PAIR_MATH(c0, f0);
    }
#undef PAIR_MATH

    a0x += __shfl_xor(a0x, 32); a1x += __shfl_xor(a1x, 32);
    a0y += __shfl_xor(a0y, 32); a1y += __shfl_xor(a1y, 32);
    float inv = 1.f / (float)(cnt > 0 ? cnt : 1);
    if (half == 0) {
        uint2 pk;
        pk.x = (unsigned int)f2bf(a0x * inv) | ((unsigned int)f2bf(a1x * inv) << 16);
        pk.y = (unsigned int)f2bf(a0y * inv) | ((unsigned int)f2bf(a1y * inv) << 16);
        *reinterpret_cast<uint2*>(A + (size_t)gw * 64 + sub * 2) = pk;
    }
}

// MFMA GEMM: out[n][0..63] = relu(q[n]·Wcat + b), q = [A(128) | feat(64)] bf16.
// A-op = weight fragments (WA), B-op = node q-rows. Wave = 16 nodes, 24 MFMAs.
__global__ void gemm_mfma_kernel(const unsigned int* __restrict__ A,
                                 const unsigned short* __restrict__ feat,
                                 const bf16x8* __restrict__ WA,
                                 const float* __restrict__ bias,
                                 unsigned short* __restrict__ out_bf,
                                 float* __restrict__ out_f,
                                 int N, int write_f32) {
    int w = threadIdx.x >> 6, lane = threadIdx.x & 63;
    int node = blockIdx.x * 64 + w * 16 + (lane & 15);
    int nc = min(node, N - 1);
    int kq = lane >> 4;                         // k-quad 0..3
    const char* arow = (const char*)A + (size_t)nc * 256 + kq * 16;
    const char* frow = (const char*)feat + (size_t)nc * 128 + kq * 16;
    bf16x8 bq[6];
    bq[0] = *(const bf16x8*)(arow);
    bq[1] = *(const bf16x8*)(arow + 64);
    bq[2] = *(const bf16x8*)(arow + 128);
    bq[3] = *(const bf16x8*)(arow + 192);
    bq[4] = *(const bf16x8*)(frow);
    bq[5] = *(const bf16x8*)(frow + 64);

    f32x4 acc0 = {0.f, 0.f, 0.f, 0.f}, acc1 = acc0, acc2 = acc0, acc3 = acc0;
#pragma unroll
    for (int kk = 0; kk < 6; ++kk) {
        bf16x8 b = bq[kk];
        acc0 = __builtin_amdgcn_mfma_f32_16x16x32_bf16(WA[(kk * 4 + 0) * 64 + lane], b, acc0, 0, 0, 0);
        acc1 = __builtin_amdgcn_mfma_f32_16x16x32_bf16(WA[(kk * 4 + 1) * 64 + lane], b, acc1, 0, 0, 0);
        acc2 = __builtin_amdgcn_mfma_f32_16x16x32_bf16(WA[(kk * 4 + 2) * 64 + lane], b, acc2, 0, 0, 0);
        acc3 = __builtin_amdgcn_mfma_f32_16x16x32_bf16(WA[(kk * 4 + 3) * 64 + lane], b, acc3, 0, 0, 0);
    }
    if (node >= N) return;

    f32x4 accs[4] = {acc0, acc1, acc2, acc3};
    int cb_hi = 4 * kq;
#pragma unroll
    for (int ct = 0; ct < 4; ++ct) {
        int cb = ct * 16 + cb_hi;               // out-col base (multiple of 4)
        float r0 = fmaxf(accs[ct][0] + bias[cb + 0], 0.f);
        float r1 = fmaxf(accs[ct][1] + bias[cb + 1], 0.f);
        float r2 = fmaxf(accs[ct][2] + bias[cb + 2], 0.f);
        float r3 = fmaxf(accs[ct][3] + bias[cb + 3], 0.f);
        if (write_f32) {
            *reinterpret_cast<float4*>(out_f + (size_t)node * 64 + cb) =
                make_float4(r0, r1, r2, r3);
        } else {
            uint2 pk;
            pk.x = (unsigned int)f2bf(r0) | ((unsigned int)f2bf(r1) << 16);
            pk.y = (unsigned int)f2bf(r2) | ((unsigned int)f2bf(r3) << 16);
            *reinterpret_cast<uint2*>(out_bf + (size_t)node * 64 + cb) = pk;
        }
    }
}

extern "C" void kernel_launch(void* const* d_in, const int* in_sizes, int n_in,
                              void* d_out, int out_size, void* d_ws, size_t ws_size,
                              hipStream_t stream) {
    const float* x   = (const float*)d_in[0];
    const int*   ei  = (const int*)d_in[1];      // int64 in reference -> int32 from harness
    const float* ea  = (const float*)d_in[2];
    const float* W1  = (const float*)d_in[3];
    const float* lw1 = (const float*)d_in[4];
    const float* b1  = (const float*)d_in[5];
    const float* W2  = (const float*)d_in[6];
    const float* lw2 = (const float*)d_in[7];
    const float* b2  = (const float*)d_in[8];

    const int N = in_sizes[0] / 64;
    const int E = in_sizes[1] / 2;

    char* p = (char*)d_ws;
    auto carve = [&](size_t bytes) -> void* {
        void* r = (void*)p;
        p += (bytes + 255) & ~(size_t)255;
        return r;
    };
    unsigned short* xb   = (unsigned short*)carve((size_t)N * 64 * 2);
    unsigned short* h    = (unsigned short*)carve((size_t)N * 64 * 2);
    unsigned int*   A    = (unsigned int*)carve((size_t)N * 64 * 4);
    bf16x8* WA      = (bf16x8*)carve(3072 * 16);
    int*   counts   = (int*)carve((size_t)N * 4);
    int*   offsets  = (int*)carve((size_t)(N + 1) * 4);
    int*   bsum     = (int*)carve(256 * 4);
    uint2* cp       = (uint2*)carve((size_t)E * 8);
    unsigned int* csr = (unsigned int*)carve((size_t)E * 4);

    const int* src = ei;
    const int* dst = ei + E;

    int n4 = N * 64 / 4;
    cvt_bf16_kernel<<<(n4 + TPB - 1) / TPB, TPB, 0, stream>>>(x, (uint2*)xb, n4, counts, N);
    build_wa_kernel<<<(3072 + TPB - 1) / TPB, TPB, 0, stream>>>(W1, lw1, W2, lw2, WA);

    int eBlocks = (E + TPB - 1) / TPB;
    count_kernel<<<eBlocks, TPB, 0, stream>>>(dst, src, ea, counts, cp, E);

    int nscan = (N + 1023) / 1024;
    scan1_kernel<<<nscan, TPB, 0, stream>>>(counts, offsets, bsum, N);
    scan2_kernel<<<1, TPB, 0, stream>>>(bsum, nscan);
    scan3_kernel<<<nscan, TPB, 0, stream>>>(offsets, bsum, N, E);

    int nphases = (N + 65535) >> 16;
    fill_kernel<<<eBlocks, TPB, 0, stream>>>(cp, offsets, csr, E, nphases);

    int aBlocks = (N + 3) / 4;            // 4 waves (nodes) per block
    int gBlocks = (N + 63) / 64;          // 4 waves x 16 nodes per block

    // Layer 1: agg on xb, then MFMA GEMM -> h (bf16)
    agg_kernel<<<aBlocks, TPB, 0, stream>>>((const unsigned int*)xb, offsets, csr, A, N);
    gemm_mfma_kernel<<<gBlocks, TPB, 0, stream>>>(A, xb, WA, b1, h, nullptr, N, 0);
    // Layer 2: agg on h, then MFMA GEMM -> d_out (fp32)
    agg_kernel<<<aBlocks, TPB, 0, stream>>>((const unsigned int*)h, offsets, csr, A, N);
    gemm_mfma_kernel<<<gBlocks, TPB, 0, stream>>>(A, h, WA + 1536, b2, nullptr, (float*)d_out, N, 1);
}

// Round 8
// 179.356 us; speedup vs baseline: 2.9091x; 1.0103x over previous
//
#include <hip/hip_runtime.h>

#define TPB 256
// NOTE: packing assumes N < 131072 (17-bit node ids) and u in [0,1]. Holds for
// this problem (N=100000, edge_attr ~ U[0,1)).

typedef __attribute__((ext_vector_type(8))) short bf16x8;
typedef __attribute__((ext_vector_type(4))) float f32x4;

#define CPAD 16   // ints per counter slot: one counter per 64B line

__device__ __forceinline__ float bf2f(unsigned short u) {
    unsigned int x = ((unsigned int)u) << 16;
    return __builtin_bit_cast(float, x);
}
__device__ __forceinline__ unsigned short f2bf(float f) {
    unsigned int u = __builtin_bit_cast(unsigned int, f);
    unsigned int r = u + 0x7FFFu + ((u >> 16) & 1u);   // round-to-nearest-even
    return (unsigned short)(r >> 16);
}

// Fused prep: bf16 convert of x (t < n4), MFMA weight-fragment build (t < 3072),
// and histogram+rank+payload pass over edges (t < E). Atomic stalls of the
// count phase overlap with the streaming cvt traffic.
// countsPad was zeroed by hipMemsetAsync before this kernel.
__global__ void prep_kernel(const float* __restrict__ x, uint2* __restrict__ xb, int n4,
                            const float* __restrict__ W1, const float* __restrict__ lw1,
                            const float* __restrict__ W2, const float* __restrict__ lw2,
                            bf16x8* __restrict__ WA,
                            const int* __restrict__ dst, const int* __restrict__ src,
                            const float* __restrict__ u, int* __restrict__ countsPad,
                            uint2* __restrict__ cp, int E) {
    int t = blockIdx.x * TPB + threadIdx.x;
    if (t < 3072) {
        int which = t / 1536;
        int rem = t - which * 1536;
        int fragid = rem >> 6;          // 0..23
        int lane = rem & 63;
        int kk = fragid >> 2, ct = fragid & 3;
        const float* W  = which ? W2  : W1;
        const float* lw = which ? lw2 : lw1;
        int col = ct * 16 + (lane & 15);
        int kbase = kk * 32 + (lane >> 4) * 8;
        short vals[8];
#pragma unroll
        for (int j = 0; j < 8; ++j) {
            int k = kbase + j;
            float v = (k < 128) ? W[(k & 1) * 4096 + (k >> 1) * 64 + col]
                                : lw[(k - 128) * 64 + col];
            vals[j] = (short)f2bf(v);
        }
        WA[t] = *reinterpret_cast<bf16x8*>(vals);
    }
    if (t < n4) {
        float4 v = reinterpret_cast<const float4*>(x)[t];
        uint2 r;
        r.x = (unsigned int)f2bf(v.x) | ((unsigned int)f2bf(v.y) << 16);
        r.y = (unsigned int)f2bf(v.z) | ((unsigned int)f2bf(v.w) << 16);
        xb[t] = r;
    }
    if (t < E) {
        int d = dst[t];
        int r = atomicAdd(&countsPad[(size_t)d * CPAD], 1);
        unsigned int uq = (unsigned int)__float2int_rn(u[t] * 32767.f);
        cp[t] = make_uint2((unsigned int)d | ((unsigned int)r << 17),
                           (unsigned int)src[t] | (uq << 17));
    }
}

// Block-level exclusive scan over padded counters, 1024 elements per block.
__global__ void scan1_kernel(const int* __restrict__ countsPad, int* __restrict__ offsets,
                             int* __restrict__ bsum, int n) {
    __shared__ int s[TPB];
    int t = threadIdx.x;
    int base = blockIdx.x * 1024 + t * 4;
    int v[4];
#pragma unroll
    for (int q = 0; q < 4; ++q) v[q] = (base + q < n) ? countsPad[(size_t)(base + q) * CPAD] : 0;
    int tsum = v[0] + v[1] + v[2] + v[3];
    s[t] = tsum;
    __syncthreads();
    for (int off = 1; off < TPB; off <<= 1) {
        int x = (t >= off) ? s[t - off] : 0;
        __syncthreads();
        s[t] += x;
        __syncthreads();
    }
    int acc = s[t] - tsum;
#pragma unroll
    for (int q = 0; q < 4; ++q) {
        if (base + q < n) offsets[base + q] = acc;
        acc += v[q];
    }
    if (t == TPB - 1) bsum[blockIdx.x] = s[TPB - 1];
}

__global__ void scan2_kernel(int* __restrict__ bsum, int nblk) {
    __shared__ int s[TPB];
    int t = threadIdx.x;
    int v = (t < nblk) ? bsum[t] : 0;
    s[t] = v;
    __syncthreads();
    for (int off = 1; off < TPB; off <<= 1) {
        int x = (t >= off) ? s[t - off] : 0;
        __syncthreads();
        s[t] += x;
        __syncthreads();
    }
    if (t < nblk) bsum[t] = s[t] - v;
}

__global__ void scan3_kernel(int* __restrict__ offsets, const int* __restrict__ bsum,
                             int n, int E) {
    int base = blockIdx.x * 1024 + threadIdx.x * 4;
    int add = bsum[blockIdx.x];
#pragma unroll
    for (int q = 0; q < 4; ++q) {
        int idx = base + q;
        if (idx < n) offsets[idx] += add;
    }
    if (blockIdx.x == 0 && threadIdx.x == 0) offsets[n] = E;
}

// Phase-partitioned scatter: phase p handles dst in [p*65536, (p+1)*65536) so the
// live csr write window (<=2.6 MB) stays L2-resident -> write combining works.
__global__ void fill_kernel(const uint2* __restrict__ cp,
                            const int* __restrict__ offsets,
                            unsigned int* __restrict__ csr, int E, int nphases) {
    int stride = gridDim.x * TPB;
    for (int p = 0; p < nphases; ++p) {
        for (int e = blockIdx.x * TPB + threadIdx.x; e < E; e += stride) {
            uint2 r = cp[e];
            int d = r.x & 0x1FFFF;
            if ((d >> 16) == p) {
                int pos = offsets[d] + (int)(r.x >> 17);
                csr[pos] = r.y;
            }
        }
    }
}

// One wave per dst node. All CSR records for the node preloaded into lanes with
// ONE vector load; edge records then come from registers (shfl), so the loop
// has a single memory hop (the feature gather). Two edges per pair-step
// (half-wave each, 4 B = 2 channels/lane), 4 pair-steps unrolled.
__global__ void agg_kernel(const unsigned int* __restrict__ featu,
                           const int* __restrict__ offsets,
                           const unsigned int* __restrict__ csr,
                           unsigned int* __restrict__ A, int N) {
    int gw = (blockIdx.x * TPB + threadIdx.x) >> 6;
    int lane = threadIdx.x & 63;
    if (gw >= N) return;
    int beg = offsets[gw], end = offsets[gw + 1];
    int cnt = end - beg;
    int half = lane >> 5, sub = lane & 31;
    const float us = 1.f / 32767.f;

    unsigned int cw = (lane < cnt) ? csr[beg + lane] : 0u;

    float a0x = 0.f, a1x = 0.f, a0y = 0.f, a1y = 0.f;  // x = ch 2*sub, y = ch 2*sub+1
    int npre = cnt < 64 ? cnt : 64;
    int npair = npre >> 1;
    int j = 0;

#define PAIR_MATH(C, F)                                                        \
    {                                                                          \
        float uu = (float)((C) >> 17) * us;                                    \
        float w0 = 1.f - uu;                                                   \
        float fx = bf2f((unsigned short)(F));                                  \
        float fy = bf2f((unsigned short)((F) >> 16));                          \
        a0x = fmaf(fx, w0, a0x); a1x = fmaf(fx, uu, a1x);                      \
        a0y = fmaf(fy, w0, a0y); a1y = fmaf(fy, uu, a1y);                      \
    }

    for (; j + 4 <= npair; j += 4) {
        unsigned int c0 = __shfl(cw, 2 * j     + half);
        unsigned int c1 = __shfl(cw, 2 * j + 2 + half);
        unsigned int c2 = __shfl(cw, 2 * j + 4 + half);
        unsigned int c3 = __shfl(cw, 2 * j + 6 + half);
        unsigned int f0 = featu[(size_t)(c0 & 0x1FFFF) * 32 + sub];
        unsigned int f1 = featu[(size_t)(c1 & 0x1FFFF) * 32 + sub];
        unsigned int f2 = featu[(size_t)(c2 & 0x1FFFF) * 32 + sub];
        unsigned int f3 = featu[(size_t)(c3 & 0x1FFFF) * 32 + sub];
        PAIR_MATH(c0, f0); PAIR_MATH(c1, f1); PAIR_MATH(c2, f2); PAIR_MATH(c3, f3);
    }
    for (; j < npair; ++j) {
        unsigned int c0 = __shfl(cw, 2 * j + half);
        unsigned int f0 = featu[(size_t)(c0 & 0x1FFFF) * 32 + sub];
        PAIR_MATH(c0, f0);
    }
    if (npre & 1) {                 // leftover edge: half 0 contributes, half 1 zero-weighted
        unsigned int c0 = __shfl(cw, npre - 1);
        unsigned int f0 = featu[(size_t)(c0 & 0x1FFFF) * 32 + sub];
        float uu = (float)(c0 >> 17) * us;
        float w0 = (half == 0) ? 1.f - uu : 0.f;
        float w1 = (half == 0) ? uu : 0.f;
        float fx = bf2f((unsigned short)f0);
        float fy = bf2f((unsigned short)(f0 >> 16));
        a0x = fmaf(fx, w0, a0x); a1x = fmaf(fx, w1, a1x);
        a0y = fmaf(fy, w0, a0y); a1y = fmaf(fy, w1, a1y);
    }
    // degree > 64 fallback (correctness only; effectively never taken)
    for (int jj = 64 + half; jj < cnt; jj += 2) {
        unsigned int c0 = csr[beg + jj];
        unsigned int f0 = featu[(size_t)(c0 & 0x1FFFF) * 32 + sub];
        PAIR_MATH(c0, f0);
    }
#undef PAIR_MATH

    a0x += __shfl_xor(a0x, 32); a1x += __shfl_xor(a1x, 32);
    a0y += __shfl_xor(a0y, 32); a1y += __shfl_xor(a1y, 32);
    float inv = 1.f / (float)(cnt > 0 ? cnt : 1);
    if (half == 0) {
        uint2 pk;
        pk.x = (unsigned int)f2bf(a0x * inv) | ((unsigned int)f2bf(a1x * inv) << 16);
        pk.y = (unsigned int)f2bf(a0y * inv) | ((unsigned int)f2bf(a1y * inv) << 16);
        *reinterpret_cast<uint2*>(A + (size_t)gw * 64 + sub * 2) = pk;
    }
}

// MFMA GEMM: out[n][0..63] = relu(q[n]·Wcat + b), q = [A(128) | feat(64)] bf16.
// A-op = weight fragments (WA), B-op = node q-rows. Wave = 16 nodes, 24 MFMAs.
__global__ void gemm_mfma_kernel(const unsigned int* __restrict__ A,
                                 const unsigned short* __restrict__ feat,
                                 const bf16x8* __restrict__ WA,
                                 const float* __restrict__ bias,
                                 unsigned short* __restrict__ out_bf,
                                 float* __restrict__ out_f,
                                 int N, int write_f32) {
    int w = threadIdx.x >> 6, lane = threadIdx.x & 63;
    int node = blockIdx.x * 64 + w * 16 + (lane & 15);
    int nc = min(node, N - 1);
    int kq = lane >> 4;                         // k-quad 0..3
    const char* arow = (const char*)A + (size_t)nc * 256 + kq * 16;
    const char* frow = (const char*)feat + (size_t)nc * 128 + kq * 16;
    bf16x8 bq[6];
    bq[0] = *(const bf16x8*)(arow);
    bq[1] = *(const bf16x8*)(arow + 64);
    bq[2] = *(const bf16x8*)(arow + 128);
    bq[3] = *(const bf16x8*)(arow + 192);
    bq[4] = *(const bf16x8*)(frow);
    bq[5] = *(const bf16x8*)(frow + 64);

    f32x4 acc0 = {0.f, 0.f, 0.f, 0.f}, acc1 = acc0, acc2 = acc0, acc3 = acc0;
#pragma unroll
    for (int kk = 0; kk < 6; ++kk) {
        bf16x8 b = bq[kk];
        acc0 = __builtin_amdgcn_mfma_f32_16x16x32_bf16(WA[(kk * 4 + 0) * 64 + lane], b, acc0, 0, 0, 0);
        acc1 = __builtin_amdgcn_mfma_f32_16x16x32_bf16(WA[(kk * 4 + 1) * 64 + lane], b, acc1, 0, 0, 0);
        acc2 = __builtin_amdgcn_mfma_f32_16x16x32_bf16(WA[(kk * 4 + 2) * 64 + lane], b, acc2, 0, 0, 0);
        acc3 = __builtin_amdgcn_mfma_f32_16x16x32_bf16(WA[(kk * 4 + 3) * 64 + lane], b, acc3, 0, 0, 0);
    }
    if (node >= N) return;

    f32x4 accs[4] = {acc0, acc1, acc2, acc3};
    int cb_hi = 4 * kq;
#pragma unroll
    for (int ct = 0; ct < 4; ++ct) {
        int cb = ct * 16 + cb_hi;               // out-col base (multiple of 4)
        float r0 = fmaxf(accs[ct][0] + bias[cb + 0], 0.f);
        float r1 = fmaxf(accs[ct][1] + bias[cb + 1], 0.f);
        float r2 = fmaxf(accs[ct][2] + bias[cb + 2], 0.f);
        float r3 = fmaxf(accs[ct][3] + bias[cb + 3], 0.f);
        if (write_f32) {
            *reinterpret_cast<float4*>(out_f + (size_t)node * 64 + cb) =
                make_float4(r0, r1, r2, r3);
        } else {
            uint2 pk;
            pk.x = (unsigned int)f2bf(r0) | ((unsigned int)f2bf(r1) << 16);
            pk.y = (unsigned int)f2bf(r2) | ((unsigned int)f2bf(r3) << 16);
            *reinterpret_cast<uint2*>(out_bf + (size_t)node * 64 + cb) = pk;
        }
    }
}

extern "C" void kernel_launch(void* const* d_in, const int* in_sizes, int n_in,
                              void* d_out, int out_size, void* d_ws, size_t ws_size,
                              hipStream_t stream) {
    const float* x   = (const float*)d_in[0];
    const int*   ei  = (const int*)d_in[1];      // int64 in reference -> int32 from harness
    const float* ea  = (const float*)d_in[2];
    const float* W1  = (const float*)d_in[3];
    const float* lw1 = (const float*)d_in[4];
    const float* b1  = (const float*)d_in[5];
    const float* W2  = (const float*)d_in[6];
    const float* lw2 = (const float*)d_in[7];
    const float* b2  = (const float*)d_in[8];

    const int N = in_sizes[0] / 64;
    const int E = in_sizes[1] / 2;

    char* p = (char*)d_ws;
    auto carve = [&](size_t bytes) -> void* {
        void* r = (void*)p;
        p += (bytes + 255) & ~(size_t)255;
        return r;
    };
    unsigned short* xb   = (unsigned short*)carve((size_t)N * 64 * 2);
    unsigned short* h    = (unsigned short*)carve((size_t)N * 64 * 2);
    unsigned int*   A    = (unsigned int*)carve((size_t)N * 64 * 4);
    bf16x8* WA      = (bf16x8*)carve(3072 * 16);
    int*   countsPad = (int*)carve((size_t)N * CPAD * 4);
    int*   offsets  = (int*)carve((size_t)(N + 1) * 4);
    int*   bsum     = (int*)carve(256 * 4);
    uint2* cp       = (uint2*)carve((size_t)E * 8);
    unsigned int* csr = (unsigned int*)carve((size_t)E * 4);

    const int* src = ei;
    const int* dst = ei + E;

    hipMemsetAsync(countsPad, 0, (size_t)N * CPAD * 4, stream);

    int n4 = N * 64 / 4;
    int prepTotal = n4 > E ? n4 : E;
    prep_kernel<<<(prepTotal + TPB - 1) / TPB, TPB, 0, stream>>>(
        x, (uint2*)xb, n4, W1, lw1, W2, lw2, WA, dst, src, ea, countsPad, cp, E);

    int nscan = (N + 1023) / 1024;
    scan1_kernel<<<nscan, TPB, 0, stream>>>(countsPad, offsets, bsum, N);
    scan2_kernel<<<1, TPB, 0, stream>>>(bsum, nscan);
    scan3_kernel<<<nscan, TPB, 0, stream>>>(offsets, bsum, N, E);

    int eBlocks = (E + TPB - 1) / TPB;
    int nphases = (N + 65535) >> 16;
    fill_kernel<<<eBlocks, TPB, 0, stream>>>(cp, offsets, csr, E, nphases);

    int aBlocks = (N + 3) / 4;            // 4 waves (nodes) per block
    int gBlocks = (N + 63) / 64;          // 4 waves x 16 nodes per block

    // Layer 1: agg on xb, then MFMA GEMM -> h (bf16)
    agg_kernel<<<aBlocks, TPB, 0, stream>>>((const unsigned int*)xb, offsets, csr, A, N);
    gemm_mfma_kernel<<<gBlocks, TPB, 0, stream>>>(A, xb, WA, b1, h, nullptr, N, 0);
    // Layer 2: agg on h, then MFMA GEMM -> d_out (fp32)
    agg_kernel<<<aBlocks, TPB, 0, stream>>>((const unsigned int*)h, offsets, csr, A, N);
    gemm_mfma_kernel<<<gBlocks, TPB, 0, stream>>>(A, h, WA + 1536, b2, nullptr, (float*)d_out, N, 1);
}

// Round 10
// 166.759 us; speedup vs baseline: 3.1289x; 1.0755x over previous
//
#include <hip/hip_runtime.h>

#define TPB 256
// NOTE: packing assumes N < 131072 (17-bit node ids) and u in [0,1]. Holds for
// this problem (N=100000, edge_attr ~ U[0,1)).

typedef __attribute__((ext_vector_type(8))) short bf16x8;
typedef __attribute__((ext_vector_type(4))) float f32x4;

__device__ __forceinline__ float bf2f(unsigned short u) {
    unsigned int x = ((unsigned int)u) << 16;
    return __builtin_bit_cast(float, x);
}
__device__ __forceinline__ unsigned short f2bf(float f) {
    unsigned int u = __builtin_bit_cast(unsigned int, f);
    unsigned int r = u + 0x7FFFu + ((u >> 16) & 1u);   // round-to-nearest-even
    return (unsigned short)(r >> 16);
}

// Fused prep: bf16 convert of x (t < n4), MFMA weight-fragment build (t < 3072),
// and histogram+rank+payload pass over edges (t < E).
// counts was zeroed by hipMemsetAsync before this kernel.
__global__ void prep_kernel(const float* __restrict__ x, uint2* __restrict__ xb, int n4,
                            const float* __restrict__ W1, const float* __restrict__ lw1,
                            const float* __restrict__ W2, const float* __restrict__ lw2,
                            bf16x8* __restrict__ WA,
                            const int* __restrict__ dst, const int* __restrict__ src,
                            const float* __restrict__ u, int* __restrict__ counts,
                            uint2* __restrict__ cp, int E) {
    int t = blockIdx.x * TPB + threadIdx.x;
    if (t < 3072) {
        int which = t / 1536;
        int rem = t - which * 1536;
        int fragid = rem >> 6;          // 0..23
        int lane = rem & 63;
        int kk = fragid >> 2, ct = fragid & 3;
        const float* W  = which ? W2  : W1;
        const float* lw = which ? lw2 : lw1;
        int col = ct * 16 + (lane & 15);
        int kbase = kk * 32 + (lane >> 4) * 8;
        short vals[8];
#pragma unroll
        for (int j = 0; j < 8; ++j) {
            int k = kbase + j;
            float v = (k < 128) ? W[(k & 1) * 4096 + (k >> 1) * 64 + col]
                                : lw[(k - 128) * 64 + col];
            vals[j] = (short)f2bf(v);
        }
        WA[t] = *reinterpret_cast<bf16x8*>(vals);
    }
    if (t < n4) {
        float4 v = reinterpret_cast<const float4*>(x)[t];
        uint2 r;
        r.x = (unsigned int)f2bf(v.x) | ((unsigned int)f2bf(v.y) << 16);
        r.y = (unsigned int)f2bf(v.z) | ((unsigned int)f2bf(v.w) << 16);
        xb[t] = r;
    }
    if (t < E) {
        int d = dst[t];
        int r = atomicAdd(&counts[d], 1);
        unsigned int uq = (unsigned int)__float2int_rn(u[t] * 32767.f);
        cp[t] = make_uint2((unsigned int)d | ((unsigned int)r << 17),
                           (unsigned int)src[t] | (uq << 17));
    }
}

// Block-level exclusive scan, 1024 elements per block (4 per thread).
__global__ void scan1_kernel(const int* __restrict__ counts, int* __restrict__ offsets,
                             int* __restrict__ bsum, int n) {
    __shared__ int s[TPB];
    int t = threadIdx.x;
    int base = blockIdx.x * 1024 + t * 4;
    int v[4];
#pragma unroll
    for (int q = 0; q < 4; ++q) v[q] = (base + q < n) ? counts[base + q] : 0;
    int tsum = v[0] + v[1] + v[2] + v[3];
    s[t] = tsum;
    __syncthreads();
    for (int off = 1; off < TPB; off <<= 1) {
        int x = (t >= off) ? s[t - off] : 0;
        __syncthreads();
        s[t] += x;
        __syncthreads();
    }
    int acc = s[t] - tsum;
#pragma unroll
    for (int q = 0; q < 4; ++q) {
        if (base + q < n) offsets[base + q] = acc;
        acc += v[q];
    }
    if (t == TPB - 1) bsum[blockIdx.x] = s[TPB - 1];
}

__global__ void scan2_kernel(int* __restrict__ bsum, int nblk) {
    __shared__ int s[TPB];
    int t = threadIdx.x;
    int v = (t < nblk) ? bsum[t] : 0;
    s[t] = v;
    __syncthreads();
    for (int off = 1; off < TPB; off <<= 1) {
        int x = (t >= off) ? s[t - off] : 0;
        __syncthreads();
        s[t] += x;
        __syncthreads();
    }
    if (t < nblk) bsum[t] = s[t] - v;
}

__global__ void scan3_kernel(int* __restrict__ offsets, const int* __restrict__ bsum,
                             int n, int E) {
    int base = blockIdx.x * 1024 + threadIdx.x * 4;
    int add = bsum[blockIdx.x];
#pragma unroll
    for (int q = 0; q < 4; ++q) {
        int idx = base + q;
        if (idx < n) offsets[idx] += add;
    }
    if (blockIdx.x == 0 && threadIdx.x == 0) offsets[n] = E;
}

// Phase-partitioned scatter: phase p handles dst in [p*65536, (p+1)*65536) so the
// live csr write window stays L2-resident -> write combining works.
__global__ void fill_kernel(const uint2* __restrict__ cp,
                            const int* __restrict__ offsets,
                            unsigned int* __restrict__ csr, int E, int nphases) {
    int stride = gridDim.x * TPB;
    for (int p = 0; p < nphases; ++p) {
        for (int e = blockIdx.x * TPB + threadIdx.x; e < E; e += stride) {
            uint2 r = cp[e];
            int d = r.x & 0x1FFFF;
            if ((d >> 16) == p) {
                int pos = offsets[d] + (int)(r.x >> 17);
                csr[pos] = r.y;
            }
        }
    }
}

// One wave per TWO dst nodes. Per node a fixed masked batch of 8 edge-pairs
// (covers degree <= 16); both nodes' 16 gathers are issued before any consume
// -> 16 loads in flight, fixed critical path. Rare direct-load tail handles
// degree > 16 and preload overflow (group > 64). Half-wave per edge: lane sub
// holds channels {2sub, 2sub+1} (one uint). Mask for batch slots is RECOMPUTED
// in the consume loop (eidx < bend) — no flag bit (bit31 belongs to the u
// field; round-9 bug).
__global__ void agg_kernel(const unsigned int* __restrict__ featu,
                           const int* __restrict__ offsets,
                           const unsigned int* __restrict__ csr,
                           unsigned int* __restrict__ A, int N) {
    int gw = (blockIdx.x * TPB + threadIdx.x) >> 6;
    int lane = threadIdx.x & 63;
    int n0 = gw * 2;
    if (n0 >= N) return;
    int half = lane >> 5, sub = lane & 31;
    const float us = 1.f / 32767.f;

    int ov = offsets[min(n0 + (lane & 3), N)];
    int o0 = __shfl(ov, 0), o1 = __shfl(ov, 1), o2 = __shfl(ov, 2);
    int beg = o0;
    int cnt = o2 - o0;                       // group edge count (both nodes)
    unsigned int cw = (lane < cnt) ? csr[beg + lane] : 0u;

    int S0 = 0, E0 = o1 - o0;                // node 0 edge range (group-local)
    int S1 = E0, E1 = cnt;                   // node 1

    // ---- issue phase: 16 independent gathers ----
    unsigned int fb[16], cs[16];
#pragma unroll
    for (int i = 0; i < 2; ++i) {
        int si = i ? S1 : S0;
        int ei = i ? E1 : E0;
        int bend = min(min(ei, si + 16), 64);
#pragma unroll
        for (int q = 0; q < 8; ++q) {
            int eidx = si + 2 * q + half;
            bool v = eidx < bend;
            unsigned int c = __shfl(cw, v ? eidx : 0);
            cs[i * 8 + q] = c;
            fb[i * 8 + q] = featu[(size_t)(c & 0x1FFFF) * 32 + sub];
        }
    }

    // ---- consume + tail + store per node ----
#pragma unroll
    for (int i = 0; i < 2; ++i) {
        int si = i ? S1 : S0;
        int ei = i ? E1 : E0;
        int bend = min(min(ei, si + 16), 64);
        float a0x = 0.f, a1x = 0.f, a0y = 0.f, a1y = 0.f;
#pragma unroll
        for (int q = 0; q < 8; ++q) {
            int eidx = si + 2 * q + half;
            float m = (eidx < bend) ? 1.f : 0.f;   // recomputed mask, no flag bit
            unsigned int c = cs[i * 8 + q];
            unsigned int f = fb[i * 8 + q];
            float uu = (float)(c >> 17) * us;
            float w1 = uu * m;
            float w0 = m - w1;
            float fx = bf2f((unsigned short)f);
            float fy = bf2f((unsigned short)(f >> 16));
            a0x = fmaf(fx, w0, a0x); a1x = fmaf(fx, w1, a1x);
            a0y = fmaf(fy, w0, a0y); a1y = fmaf(fy, w1, a1y);
        }
        int tstart = max(si, bend);
        for (int t = tstart + half; t < ei; t += 2) {   // rare tail (deg>16 / preload overflow)
            unsigned int c = csr[beg + t];
            unsigned int f = featu[(size_t)(c & 0x1FFFF) * 32 + sub];
            float uu = (float)(c >> 17) * us;
            float w0 = 1.f - uu;
            float fx = bf2f((unsigned short)f);
            float fy = bf2f((unsigned short)(f >> 16));
            a0x = fmaf(fx, w0, a0x); a1x = fmaf(fx, uu, a1x);
            a0y = fmaf(fy, w0, a0y); a1y = fmaf(fy, uu, a1y);
        }
        a0x += __shfl_xor(a0x, 32); a1x += __shfl_xor(a1x, 32);
        a0y += __shfl_xor(a0y, 32); a1y += __shfl_xor(a1y, 32);
        int node = n0 + i;
        int cN = ei - si;
        float inv = 1.f / (float)(cN > 0 ? cN : 1);
        if (half == 0 && node < N) {
            uint2 pk;
            pk.x = (unsigned int)f2bf(a0x * inv) | ((unsigned int)f2bf(a1x * inv) << 16);
            pk.y = (unsigned int)f2bf(a0y * inv) | ((unsigned int)f2bf(a1y * inv) << 16);
            *reinterpret_cast<uint2*>(A + (size_t)node * 64 + sub * 2) = pk;
        }
    }
}

// MFMA GEMM: out[n][0..63] = relu(q[n]·Wcat + b), q = [A(128) | feat(64)] bf16.
// A-op = weight fragments (WA), B-op = node q-rows. Wave = 16 nodes, 24 MFMAs.
__global__ void gemm_mfma_kernel(const unsigned int* __restrict__ A,
                                 const unsigned short* __restrict__ feat,
                                 const bf16x8* __restrict__ WA,
                                 const float* __restrict__ bias,
                                 unsigned short* __restrict__ out_bf,
                                 float* __restrict__ out_f,
                                 int N, int write_f32) {
    int w = threadIdx.x >> 6, lane = threadIdx.x & 63;
    int node = blockIdx.x * 64 + w * 16 + (lane & 15);
    int nc = min(node, N - 1);
    int kq = lane >> 4;                         // k-quad 0..3
    const char* arow = (const char*)A + (size_t)nc * 256 + kq * 16;
    const char* frow = (const char*)feat + (size_t)nc * 128 + kq * 16;
    bf16x8 bq[6];
    bq[0] = *(const bf16x8*)(arow);
    bq[1] = *(const bf16x8*)(arow + 64);
    bq[2] = *(const bf16x8*)(arow + 128);
    bq[3] = *(const bf16x8*)(arow + 192);
    bq[4] = *(const bf16x8*)(frow);
    bq[5] = *(const bf16x8*)(frow + 64);

    f32x4 acc0 = {0.f, 0.f, 0.f, 0.f}, acc1 = acc0, acc2 = acc0, acc3 = acc0;
#pragma unroll
    for (int kk = 0; kk < 6; ++kk) {
        bf16x8 b = bq[kk];
        acc0 = __builtin_amdgcn_mfma_f32_16x16x32_bf16(WA[(kk * 4 + 0) * 64 + lane], b, acc0, 0, 0, 0);
        acc1 = __builtin_amdgcn_mfma_f32_16x16x32_bf16(WA[(kk * 4 + 1) * 64 + lane], b, acc1, 0, 0, 0);
        acc2 = __builtin_amdgcn_mfma_f32_16x16x32_bf16(WA[(kk * 4 + 2) * 64 + lane], b, acc2, 0, 0, 0);
        acc3 = __builtin_amdgcn_mfma_f32_16x16x32_bf16(WA[(kk * 4 + 3) * 64 + lane], b, acc3, 0, 0, 0);
    }
    if (node >= N) return;

    f32x4 accs[4] = {acc0, acc1, acc2, acc3};
    int cb_hi = 4 * kq;
#pragma unroll
    for (int ct = 0; ct < 4; ++ct) {
        int cb = ct * 16 + cb_hi;               // out-col base (multiple of 4)
        float r0 = fmaxf(accs[ct][0] + bias[cb + 0], 0.f);
        float r1 = fmaxf(accs[ct][1] + bias[cb + 1], 0.f);
        float r2 = fmaxf(accs[ct][2] + bias[cb + 2], 0.f);
        float r3 = fmaxf(accs[ct][3] + bias[cb + 3], 0.f);
        if (write_f32) {
            *reinterpret_cast<float4*>(out_f + (size_t)node * 64 + cb) =
                make_float4(r0, r1, r2, r3);
        } else {
            uint2 pk;
            pk.x = (unsigned int)f2bf(r0) | ((unsigned int)f2bf(r1) << 16);
            pk.y = (unsigned int)f2bf(r2) | ((unsigned int)f2bf(r3) << 16);
            *reinterpret_cast<uint2*>(out_bf + (size_t)node * 64 + cb) = pk;
        }
    }
}

extern "C" void kernel_launch(void* const* d_in, const int* in_sizes, int n_in,
                              void* d_out, int out_size, void* d_ws, size_t ws_size,
                              hipStream_t stream) {
    const float* x   = (const float*)d_in[0];
    const int*   ei  = (const int*)d_in[1];      // int64 in reference -> int32 from harness
    const float* ea  = (const float*)d_in[2];
    const float* W1  = (const float*)d_in[3];
    const float* lw1 = (const float*)d_in[4];
    const float* b1  = (const float*)d_in[5];
    const float* W2  = (const float*)d_in[6];
    const float* lw2 = (const float*)d_in[7];
    const float* b2  = (const float*)d_in[8];

    const int N = in_sizes[0] / 64;
    const int E = in_sizes[1] / 2;

    char* p = (char*)d_ws;
    auto carve = [&](size_t bytes) -> void* {
        void* r = (void*)p;
        p += (bytes + 255) & ~(size_t)255;
        return r;
    };
    unsigned short* xb   = (unsigned short*)carve((size_t)N * 64 * 2);
    unsigned short* h    = (unsigned short*)carve((size_t)N * 64 * 2);
    unsigned int*   A    = (unsigned int*)carve((size_t)N * 64 * 4);
    bf16x8* WA      = (bf16x8*)carve(3072 * 16);
    int*   counts   = (int*)carve((size_t)N * 4);
    int*   offsets  = (int*)carve((size_t)(N + 1) * 4);
    int*   bsum     = (int*)carve(256 * 4);
    uint2* cp       = (uint2*)carve((size_t)E * 8);
    unsigned int* csr = (unsigned int*)carve((size_t)E * 4);

    const int* src = ei;
    const int* dst = ei + E;

    hipMemsetAsync(counts, 0, (size_t)N * 4, stream);

    int n4 = N * 64 / 4;
    int prepTotal = n4 > E ? n4 : E;
    prep_kernel<<<(prepTotal + TPB - 1) / TPB, TPB, 0, stream>>>(
        x, (uint2*)xb, n4, W1, lw1, W2, lw2, WA, dst, src, ea, counts, cp, E);

    int nscan = (N + 1023) / 1024;
    scan1_kernel<<<nscan, TPB, 0, stream>>>(counts, offsets, bsum, N);
    scan2_kernel<<<1, TPB, 0, stream>>>(bsum, nscan);
    scan3_kernel<<<nscan, TPB, 0, stream>>>(offsets, bsum, N, E);

    int eBlocks = (E + TPB - 1) / TPB;
    int nphases = (N + 65535) >> 16;
    fill_kernel<<<eBlocks, TPB, 0, stream>>>(cp, offsets, csr, E, nphases);

    int nwaves = (N + 1) / 2;             // 2 nodes per wave
    int aBlocks = (nwaves + 3) / 4;       // 4 waves per block
    int gBlocks = (N + 63) / 64;          // 4 waves x 16 nodes per block

    // Layer 1: agg on xb, then MFMA GEMM -> h (bf16)
    agg_kernel<<<aBlocks, TPB, 0, stream>>>((const unsigned int*)xb, offsets, csr, A, N);
    gemm_mfma_kernel<<<gBlocks, TPB, 0, stream>>>(A, xb, WA, b1, h, nullptr, N, 0);
    // Layer 2: agg on h, then MFMA GEMM -> d_out (fp32)
    agg_kernel<<<aBlocks, TPB, 0, stream>>>((const unsigned int*)h, offsets, csr, A, N);
    gemm_mfma_kernel<<<gBlocks, TPB, 0, stream>>>(A, h, WA + 1536, b2, nullptr, (float*)d_out, N, 1);
}

// Round 11
// 146.606 us; speedup vs baseline: 3.5590x; 1.1375x over previous
//
#include <hip/hip_runtime.h>

#define TPB 256
// NOTE: packing assumes N < 131072 (17-bit node ids) and u in [0,1]. Holds for
// this problem (N=100000, edge_attr ~ U[0,1)).

typedef __attribute__((ext_vector_type(8))) short bf16x8;
typedef __attribute__((ext_vector_type(4))) float f32x4;

__device__ __forceinline__ float bf2f(unsigned short u) {
    unsigned int x = ((unsigned int)u) << 16;
    return __builtin_bit_cast(float, x);
}
__device__ __forceinline__ unsigned short f2bf(float f) {
    unsigned int u = __builtin_bit_cast(unsigned int, f);
    unsigned int r = u + 0x7FFFu + ((u >> 16) & 1u);   // round-to-nearest-even
    return (unsigned short)(r >> 16);
}

// Fused prep: bf16 convert of x (t < n4), MFMA weight-fragment build (t < 3072),
// and histogram+rank+payload pass over edges (t < E).
// counts was zeroed by hipMemsetAsync before this kernel.
__global__ void prep_kernel(const float* __restrict__ x, uint2* __restrict__ xb, int n4,
                            const float* __restrict__ W1, const float* __restrict__ lw1,
                            const float* __restrict__ W2, const float* __restrict__ lw2,
                            bf16x8* __restrict__ WA,
                            const int* __restrict__ dst, const int* __restrict__ src,
                            const float* __restrict__ u, int* __restrict__ counts,
                            uint2* __restrict__ cp, int E) {
    int t = blockIdx.x * TPB + threadIdx.x;
    if (t < 3072) {
        int which = t / 1536;
        int rem = t - which * 1536;
        int fragid = rem >> 6;          // 0..23
        int lane = rem & 63;
        int kk = fragid >> 2, ct = fragid & 3;
        const float* W  = which ? W2  : W1;
        const float* lw = which ? lw2 : lw1;
        int col = ct * 16 + (lane & 15);
        int kbase = kk * 32 + (lane >> 4) * 8;
        short vals[8];
#pragma unroll
        for (int j = 0; j < 8; ++j) {
            int k = kbase + j;
            float v = (k < 128) ? W[(k & 1) * 4096 + (k >> 1) * 64 + col]
                                : lw[(k - 128) * 64 + col];
            vals[j] = (short)f2bf(v);
        }
        WA[t] = *reinterpret_cast<bf16x8*>(vals);
    }
    if (t < n4) {
        float4 v = reinterpret_cast<const float4*>(x)[t];
        uint2 r;
        r.x = (unsigned int)f2bf(v.x) | ((unsigned int)f2bf(v.y) << 16);
        r.y = (unsigned int)f2bf(v.z) | ((unsigned int)f2bf(v.w) << 16);
        xb[t] = r;
    }
    if (t < E) {
        int d = dst[t];
        int r = atomicAdd(&counts[d], 1);
        unsigned int uq = (unsigned int)__float2int_rn(u[t] * 32767.f);
        cp[t] = make_uint2((unsigned int)d | ((unsigned int)r << 17),
                           (unsigned int)src[t] | (uq << 17));
    }
}

// Block-level exclusive scan, 1024 elements per block (4 per thread).
__global__ void scan1_kernel(const int* __restrict__ counts, int* __restrict__ offsets,
                             int* __restrict__ bsum, int n) {
    __shared__ int s[TPB];
    int t = threadIdx.x;
    int base = blockIdx.x * 1024 + t * 4;
    int v[4];
#pragma unroll
    for (int q = 0; q < 4; ++q) v[q] = (base + q < n) ? counts[base + q] : 0;
    int tsum = v[0] + v[1] + v[2] + v[3];
    s[t] = tsum;
    __syncthreads();
    for (int off = 1; off < TPB; off <<= 1) {
        int x = (t >= off) ? s[t - off] : 0;
        __syncthreads();
        s[t] += x;
        __syncthreads();
    }
    int acc = s[t] - tsum;
#pragma unroll
    for (int q = 0; q < 4; ++q) {
        if (base + q < n) offsets[base + q] = acc;
        acc += v[q];
    }
    if (t == TPB - 1) bsum[blockIdx.x] = s[TPB - 1];
}

__global__ void scan2_kernel(int* __restrict__ bsum, int nblk) {
    __shared__ int s[TPB];
    int t = threadIdx.x;
    int v = (t < nblk) ? bsum[t] : 0;
    s[t] = v;
    __syncthreads();
    for (int off = 1; off < TPB; off <<= 1) {
        int x = (t >= off) ? s[t - off] : 0;
        __syncthreads();
        s[t] += x;
        __syncthreads();
    }
    if (t < nblk) bsum[t] = s[t] - v;
}

__global__ void scan3_kernel(int* __restrict__ offsets, const int* __restrict__ bsum,
                             int n, int E) {
    int base = blockIdx.x * 1024 + threadIdx.x * 4;
    int add = bsum[blockIdx.x];
#pragma unroll
    for (int q = 0; q < 4; ++q) {
        int idx = base + q;
        if (idx < n) offsets[idx] += add;
    }
    if (blockIdx.x == 0 && threadIdx.x == 0) offsets[n] = E;
}

// Phase-partitioned scatter: phase p handles dst in [p*65536, (p+1)*65536) so the
// live csr write window stays L2-resident -> write combining works.
__global__ void fill_kernel(const uint2* __restrict__ cp,
                            const int* __restrict__ offsets,
                            unsigned int* __restrict__ csr, int E, int nphases) {
    int stride = gridDim.x * TPB;
    for (int p = 0; p < nphases; ++p) {
        for (int e = blockIdx.x * TPB + threadIdx.x; e < E; e += stride) {
            uint2 r = cp[e];
            int d = r.x & 0x1FFFF;
            if ((d >> 16) == p) {
                int pos = offsets[d] + (int)(r.x >> 17);
                csr[pos] = r.y;
            }
        }
    }
}

// Fused agg + MFMA gemm. Block = 4 waves = 16 nodes.
// agg phase: wave wid aggregates nodes nb+4*wid+{0..3} as two 2-node batches
// (r10 fixed masked 8-pair pipeline, 16 gathers in flight); A-rows (interleaved
// a0/a1 bf16 pairs, 256B/node) go to LDS (stride 68 uints keeps rows 16B-aligned).
// gemm phase: wave wid = col-tile ct, 6 MFMAs over k; B-frag k<128 from LDS,
// k>=128 from feat; epilogue bias+relu, store bf16 (layer1) or f32 (layer2).
__global__ void fused_kernel(const unsigned int* __restrict__ featu,
                             const int* __restrict__ offsets,
                             const unsigned int* __restrict__ csr,
                             const bf16x8* __restrict__ WA,
                             const float* __restrict__ bias,
                             unsigned short* __restrict__ out_bf,
                             float* __restrict__ out_f,
                             int N, int write_f32) {
    __shared__ unsigned int lds[16 * 68];
    int wid = threadIdx.x >> 6, lane = threadIdx.x & 63;
    int nb = blockIdx.x * 16;
    int half = lane >> 5, sub = lane & 31;
    const float us = 1.f / 32767.f;

#pragma unroll
    for (int batch = 0; batch < 2; ++batch) {
        int n0 = nb + wid * 4 + batch * 2;
        int ov = offsets[min(n0 + (lane & 3), N)];
        int o0 = __shfl(ov, 0), o1 = __shfl(ov, 1), o2 = __shfl(ov, 2);
        int beg = o0;
        int cnt = o2 - o0;                       // group edge count (2 nodes)
        unsigned int cw = (lane < cnt) ? csr[beg + lane] : 0u;
        int S0 = 0, E0 = o1 - o0, S1 = E0, E1 = cnt;

        // ---- issue phase: 16 independent gathers ----
        unsigned int fb[16], cs[16];
#pragma unroll
        for (int i = 0; i < 2; ++i) {
            int si = i ? S1 : S0;
            int ei = i ? E1 : E0;
            int bend = min(min(ei, si + 16), 64);
#pragma unroll
            for (int q = 0; q < 8; ++q) {
                int eidx = si + 2 * q + half;
                bool v = eidx < bend;
                unsigned int c = __shfl(cw, v ? eidx : 0);
                cs[i * 8 + q] = c;
                fb[i * 8 + q] = featu[(size_t)(c & 0x1FFFF) * 32 + sub];
            }
        }

        // ---- consume + tail + LDS store per node ----
#pragma unroll
        for (int i = 0; i < 2; ++i) {
            int si = i ? S1 : S0;
            int ei = i ? E1 : E0;
            int bend = min(min(ei, si + 16), 64);
            float a0x = 0.f, a1x = 0.f, a0y = 0.f, a1y = 0.f;
#pragma unroll
            for (int q = 0; q < 8; ++q) {
                int eidx = si + 2 * q + half;
                float m = (eidx < bend) ? 1.f : 0.f;   // recomputed mask, no flag bit
                unsigned int c = cs[i * 8 + q];
                unsigned int f = fb[i * 8 + q];
                float uu = (float)(c >> 17) * us;
                float w1 = uu * m;
                float w0 = m - w1;
                float fx = bf2f((unsigned short)f);
                float fy = bf2f((unsigned short)(f >> 16));
                a0x = fmaf(fx, w0, a0x); a1x = fmaf(fx, w1, a1x);
                a0y = fmaf(fy, w0, a0y); a1y = fmaf(fy, w1, a1y);
            }
            int tstart = max(si, bend);
            for (int t = tstart + half; t < ei; t += 2) {   // rare tail
                unsigned int c = csr[beg + t];
                unsigned int f = featu[(size_t)(c & 0x1FFFF) * 32 + sub];
                float uu = (float)(c >> 17) * us;
                float w0 = 1.f - uu;
                float fx = bf2f((unsigned short)f);
                float fy = bf2f((unsigned short)(f >> 16));
                a0x = fmaf(fx, w0, a0x); a1x = fmaf(fx, uu, a1x);
                a0y = fmaf(fy, w0, a0y); a1y = fmaf(fy, uu, a1y);
            }
            a0x += __shfl_xor(a0x, 32); a1x += __shfl_xor(a1x, 32);
            a0y += __shfl_xor(a0y, 32); a1y += __shfl_xor(a1y, 32);
            int cN = ei - si;
            float inv = 1.f / (float)(cN > 0 ? cN : 1);
            if (half == 0) {
                int nrel = n0 + i - nb;          // 0..15 always
                uint2 pk;
                pk.x = (unsigned int)f2bf(a0x * inv) | ((unsigned int)f2bf(a1x * inv) << 16);
                pk.y = (unsigned int)f2bf(a0y * inv) | ((unsigned int)f2bf(a1y * inv) << 16);
                *reinterpret_cast<uint2*>(&lds[nrel * 68 + sub * 2]) = pk;
            }
        }
    }
    __syncthreads();

    // ---- gemm phase: wave wid = col-tile ----
    int node = nb + (lane & 15);
    int nc = min(node, N - 1);
    int kq = lane >> 4;                          // k-quad 0..3
    const unsigned int* arow = &lds[(lane & 15) * 68 + kq * 4];
    const char* frow = (const char*)featu + (size_t)nc * 128 + kq * 16;
    bf16x8 bq[6];
    bq[0] = *reinterpret_cast<const bf16x8*>(arow);
    bq[1] = *reinterpret_cast<const bf16x8*>(arow + 16);
    bq[2] = *reinterpret_cast<const bf16x8*>(arow + 32);
    bq[3] = *reinterpret_cast<const bf16x8*>(arow + 48);
    bq[4] = *reinterpret_cast<const bf16x8*>(frow);
    bq[5] = *reinterpret_cast<const bf16x8*>(frow + 64);

    f32x4 acc = {0.f, 0.f, 0.f, 0.f};
#pragma unroll
    for (int kk = 0; kk < 6; ++kk)
        acc = __builtin_amdgcn_mfma_f32_16x16x32_bf16(WA[(kk * 4 + wid) * 64 + lane],
                                                      bq[kk], acc, 0, 0, 0);
    if (node >= N) return;

    int cb = wid * 16 + 4 * kq;                  // out-col base (multiple of 4)
    float r0 = fmaxf(acc[0] + bias[cb + 0], 0.f);
    float r1 = fmaxf(acc[1] + bias[cb + 1], 0.f);
    float r2 = fmaxf(acc[2] + bias[cb + 2], 0.f);
    float r3 = fmaxf(acc[3] + bias[cb + 3], 0.f);
    if (write_f32) {
        *reinterpret_cast<float4*>(out_f + (size_t)node * 64 + cb) =
            make_float4(r0, r1, r2, r3);
    } else {
        uint2 pk;
        pk.x = (unsigned int)f2bf(r0) | ((unsigned int)f2bf(r1) << 16);
        pk.y = (unsigned int)f2bf(r2) | ((unsigned int)f2bf(r3) << 16);
        *reinterpret_cast<uint2*>(out_bf + (size_t)node * 64 + cb) = pk;
    }
}

extern "C" void kernel_launch(void* const* d_in, const int* in_sizes, int n_in,
                              void* d_out, int out_size, void* d_ws, size_t ws_size,
                              hipStream_t stream) {
    const float* x   = (const float*)d_in[0];
    const int*   ei  = (const int*)d_in[1];      // int64 in reference -> int32 from harness
    const float* ea  = (const float*)d_in[2];
    const float* W1  = (const float*)d_in[3];
    const float* lw1 = (const float*)d_in[4];
    const float* b1  = (const float*)d_in[5];
    const float* W2  = (const float*)d_in[6];
    const float* lw2 = (const float*)d_in[7];
    const float* b2  = (const float*)d_in[8];

    const int N = in_sizes[0] / 64;
    const int E = in_sizes[1] / 2;

    char* p = (char*)d_ws;
    auto carve = [&](size_t bytes) -> void* {
        void* r = (void*)p;
        p += (bytes + 255) & ~(size_t)255;
        return r;
    };
    unsigned short* xb   = (unsigned short*)carve((size_t)N * 64 * 2);
    unsigned short* h    = (unsigned short*)carve((size_t)N * 64 * 2);
    bf16x8* WA      = (bf16x8*)carve(3072 * 16);
    int*   counts   = (int*)carve((size_t)N * 4);
    int*   offsets  = (int*)carve((size_t)(N + 1) * 4);
    int*   bsum     = (int*)carve(256 * 4);
    uint2* cp       = (uint2*)carve((size_t)E * 8);
    unsigned int* csr = (unsigned int*)carve((size_t)E * 4);

    const int* src = ei;
    const int* dst = ei + E;

    hipMemsetAsync(counts, 0, (size_t)N * 4, stream);

    int n4 = N * 64 / 4;
    int prepTotal = n4 > E ? n4 : E;
    prep_kernel<<<(prepTotal + TPB - 1) / TPB, TPB, 0, stream>>>(
        x, (uint2*)xb, n4, W1, lw1, W2, lw2, WA, dst, src, ea, counts, cp, E);

    int nscan = (N + 1023) / 1024;
    scan1_kernel<<<nscan, TPB, 0, stream>>>(counts, offsets, bsum, N);
    scan2_kernel<<<1, TPB, 0, stream>>>(bsum, nscan);
    scan3_kernel<<<nscan, TPB, 0, stream>>>(offsets, bsum, N, E);

    int eBlocks = (E + TPB - 1) / TPB;
    int nphases = (N + 65535) >> 16;
    fill_kernel<<<eBlocks, TPB, 0, stream>>>(cp, offsets, csr, E, nphases);

    int fBlocks = (N + 15) / 16;          // 16 nodes per block

    // Layer 1: fused agg+gemm on xb -> h (bf16)
    fused_kernel<<<fBlocks, TPB, 0, stream>>>((const unsigned int*)xb, offsets, csr,
                                              WA, b1, h, nullptr, N, 0);
    // Layer 2: fused agg+gemm on h -> d_out (fp32)
    fused_kernel<<<fBlocks, TPB, 0, stream>>>((const unsigned int*)h, offsets, csr,
                                              WA + 1536, b2, nullptr, (float*)d_out, N, 1);
}